// Round 4
// baseline (14730.168 us; speedup 1.0000x reference)
//
#include <hip/hip_runtime.h>

// DecoderGRU: 2-layer GRU (B=64, H=1024, T=1024, OUT=128) + output projection.
// Persistent cooperative kernel, software-pipelined across layers:
//   super-step s: L0 computes y0_s | L1 computes y1_{s-1} | PROJ writes out_{s-2}
// R4: h reads go through the CACHED path (L1/L2, ~60 B/cyc/CU + cross-CU
// L2 sharing) instead of sc0sc1 bypass (~8 B/cyc/CU fabric rate, R3's limit).
// Coherence: one elected block per physical XCD (HW_REG_XCC_ID) executes
// buffer_inv sc0 sc1 (L2 inv) per step; every wave does a local L1 inv.
// All global stores during the loop are sc0 sc1 (L2 never dirty -> inv-safe).

#define NWORK 200
#define NBLK 201
#define SMEM_BYTES 150208
#define H 1024
#define T 1024

typedef short s16x8 __attribute__((ext_vector_type(8)));
typedef float f32x4 __attribute__((ext_vector_type(4)));
typedef unsigned long long u64;

__device__ __forceinline__ unsigned short f2bf(float f) {
  union { float f; unsigned u; } v; v.f = f;
  return (unsigned short)((v.u + 0x7FFFu + ((v.u >> 16) & 1u)) >> 16);
}
__device__ __forceinline__ float sigm(float x) { return 1.f / (1.f + __expf(-x)); }

__device__ __forceinline__ void st_u16(void* p, unsigned short v) {
  __hip_atomic_store((unsigned short*)p, v, __ATOMIC_RELAXED, __HIP_MEMORY_SCOPE_AGENT);
}

// ---- cached 16B loads (L1/L2 path; coherence via per-step inv) ----
#define GLD(d, p, off) \
  asm volatile("global_load_dwordx4 %0, %1, off offset:" #off \
               : "=v"(d) : "v"(p))
#define GLD16A(A, p) \
  GLD(A[0],p,0);    GLD(A[1],p,64);   GLD(A[2],p,128);  GLD(A[3],p,192);  \
  GLD(A[4],p,256);  GLD(A[5],p,320);  GLD(A[6],p,384);  GLD(A[7],p,448);  \
  GLD(A[8],p,512);  GLD(A[9],p,576);  GLD(A[10],p,640); GLD(A[11],p,704); \
  GLD(A[12],p,768); GLD(A[13],p,832); GLD(A[14],p,896); GLD(A[15],p,960)
#define GLD16B(A, p) \
  GLD(A[0],p,1024); GLD(A[1],p,1088); GLD(A[2],p,1152); GLD(A[3],p,1216); \
  GLD(A[4],p,1280); GLD(A[5],p,1344); GLD(A[6],p,1408); GLD(A[7],p,1472); \
  GLD(A[8],p,1536); GLD(A[9],p,1600); GLD(A[10],p,1664); GLD(A[11],p,1728); \
  GLD(A[12],p,1792); GLD(A[13],p,1856); GLD(A[14],p,1920); GLD(A[15],p,1984)
#define WAITV(n) asm volatile("s_waitcnt vmcnt(" #n ")" ::: "memory")
#define INVL1()  asm volatile("buffer_inv" ::: "memory")   // L1-only, local
#define TIE16(A) \
  asm volatile("" : "+v"(A[0]),"+v"(A[1]),"+v"(A[2]),"+v"(A[3]), \
                    "+v"(A[4]),"+v"(A[5]),"+v"(A[6]),"+v"(A[7]), \
                    "+v"(A[8]),"+v"(A[9]),"+v"(A[10]),"+v"(A[11]), \
                    "+v"(A[12]),"+v"(A[13]),"+v"(A[14]),"+v"(A[15]))

__device__ __forceinline__ void gst16(s16x8 v, void* p) {
  asm volatile("global_store_dwordx4 %0, %1, off sc0 sc1" :: "v"(p), "v"(v) : "memory");
}
__device__ __forceinline__ void gst4(float v, void* p) {
  asm volatile("global_store_dword %0, %1, off sc0 sc1" :: "v"(p), "v"(v) : "memory");
}

// Worker barrier + coherence: drain own sc1 stores, arrive, wait epoch, then
// elect one block per physical XCD to invalidate that XCD's L2 (producers'
// data sits in IF$; L2 holds only stale clean lines since no loop store
// dirties L2). Others wait on the XCD's done-flag. Per-step counter arrays
// avoid reset races.
__device__ __forceinline__ void bar_worker(unsigned* ctr, unsigned* epoch,
                                           unsigned* xcnt, unsigned* xdone,
                                           unsigned xcd, unsigned phase,
                                           int tid, int bid) {
  WAITV(0);
  __syncthreads();
  if (tid == 0) {
    __hip_atomic_fetch_add(ctr + (bid >> 3) * 32, 1u,
                           __ATOMIC_RELAXED, __HIP_MEMORY_SCOPE_AGENT);
    while (__hip_atomic_load(epoch, __ATOMIC_RELAXED, __HIP_MEMORY_SCOPE_AGENT) < phase)
      __builtin_amdgcn_s_sleep(1);
    unsigned v = __hip_atomic_fetch_add(xcnt + (phase * 8u + xcd) * 4u, 1u,
                                        __ATOMIC_RELAXED, __HIP_MEMORY_SCOPE_AGENT);
    if (v == 0) {
      asm volatile("buffer_inv sc0 sc1" ::: "memory");   // this XCD's L2
      asm volatile("s_waitcnt vmcnt(0)" ::: "memory");
      __hip_atomic_store(xdone + xcd * 16, phase,
                         __ATOMIC_RELAXED, __HIP_MEMORY_SCOPE_AGENT);
    } else {
      while (__hip_atomic_load(xdone + xcd * 16, __ATOMIC_RELAXED,
                               __HIP_MEMORY_SCOPE_AGENT) < phase)
        __builtin_amdgcn_s_sleep(1);
    }
  }
  __syncthreads();
}

extern "C" __global__ void __launch_bounds__(512, 2)
gru_pipeline(const float* __restrict__ z,
             const float* __restrict__ Whh0,
             const float* __restrict__ bih0, const float* __restrict__ bhh0,
             const float* __restrict__ Wih1, const float* __restrict__ Whh1,
             const float* __restrict__ bih1, const float* __restrict__ bhh1,
             const float* __restrict__ Wout, const float* __restrict__ bout,
             float* __restrict__ out,
             unsigned short* __restrict__ h0buf,   // [2][64*1024] bf16
             unsigned short* __restrict__ h1buf,   // [2][64*1024] bf16
             unsigned* __restrict__ ctr,           // 25 x 128B-spaced counters
             unsigned* __restrict__ epoch,
             unsigned* __restrict__ xcnt,          // [1028][8] 16B-spaced
             unsigned* __restrict__ xdone)         // [8] 64B-spaced
{
  extern __shared__ char smem[];
  const int tid  = threadIdx.x;
  const int lane = tid & 63;
  const int w    = tid >> 6;
  const int bid  = blockIdx.x;

  // physical XCD of this CU (HW_REG_XCC_ID = hwreg 20) [measured m09]
  unsigned xcd = __builtin_amdgcn_s_getreg((20) | (0 << 6) | (31 << 11)) & 7u;

  // ---------------- coordinator block: barrier engine only ----------------
  if (bid == NWORK) {
    if (w == 0) {
      for (unsigned phase = 1; phase <= 1027; ++phase) {
        const unsigned tgt = 8u * phase;
        unsigned* c = ctr + (lane < 25 ? lane : 0) * 32;
        for (;;) {
          unsigned v0 = __hip_atomic_load(c, __ATOMIC_RELAXED, __HIP_MEMORY_SCOPE_AGENT);
          unsigned v = (lane < 25) ? v0 : tgt;
          if (__ballot(v < tgt) == 0ull) break;
          __builtin_amdgcn_s_sleep(2);
        }
        if (lane == 0)
          __hip_atomic_store(epoch, phase, __ATOMIC_RELAXED, __HIP_MEMORY_SCOPE_AGENT);
      }
    }
    return;
  }

  int role, base;
  if (bid < 64)       { role = 0; base = bid * 16; }        // layer 0: 16 units
  else if (bid < 192) { role = 1; base = (bid - 64) * 8; }  // layer 1: 8 units
  else                { role = 2; base = (bid - 192) * 16; }// proj: 16 out cols

  unsigned short* frag = (unsigned short*)smem;

  // ---------------- init: build bf16 B-fragments in LDS, prefill states ----
  if (role == 0) {
    float* bi = (float*)(smem + 114944);
    float* bh = (float*)(smem + 115136);
    float* hm = (float*)(smem + 110848);
    for (int p = tid; p < 6144; p += 512) {
      int c = p % 48; int r2 = p / 48; int grp = r2 & 3; int kb = r2 >> 2;
      int g = c >> 4, u = c & 15;
      unsigned short* dst = frag + (kb*3 + g)*512 + (grp*16 + u)*8;
      const float* s = Whh0 + (size_t)(g*H + base + u)*H + kb*32 + grp*8;
      #pragma unroll
      for (int j = 0; j < 8; ++j) dst[j] = f2bf(s[j]);
    }
    if (tid < 48) {
      int g = tid >> 4, u = tid & 15;
      bi[tid] = bih0[g*H + base + u];
      bh[tid] = bhh0[g*H + base + u];
    }
    for (int p = tid; p < 1024; p += 512) {
      int b = p >> 4, u = p & 15;
      float v = z[b*H + base + u];
      hm[p] = v;
      st_u16(&h0buf[65536 + b*H + base + u], f2bf(v));   // y0_{-1} := z
    }
  } else if (role == 1) {
    float* bi = (float*)(smem + 150016);
    float* bh = (float*)(smem + 150112);
    float* hm = (float*)(smem + 147968);
    for (int p = tid; p < 8192; p += 512) {
      int c = p & 31, grp = (p >> 5) & 3, kb = (p >> 7) & 31, gm = p >> 12;
      unsigned short* dst = frag + gm*32768 + (kb*2 + (c>>4))*512 + (grp*16 + (c&15))*8;
      if (c < 24) {
        int g = c >> 3, u = c & 7;
        const float* W = gm ? Whh1 : Wih1;
        const float* s = W + (size_t)(g*H + base + u)*H + kb*32 + grp*8;
        #pragma unroll
        for (int j = 0; j < 8; ++j) dst[j] = f2bf(s[j]);
      } else {
        #pragma unroll
        for (int j = 0; j < 8; ++j) dst[j] = 0;
      }
    }
    if (tid < 24) {
      int g = tid >> 3, u = tid & 7;
      bi[tid] = bih1[g*H + base + u];
      bh[tid] = bhh1[g*H + base + u];
    }
    {
      int b = tid >> 3, u = tid & 7;
      float v = z[b*H + base + u];
      hm[tid] = v;
      st_u16(&h1buf[65536 + b*H + base + u], f2bf(v));   // y1_{-1} := z
    }
  } else {
    float* bo = (float*)(smem + 32768);
    for (int p = tid; p < 2048; p += 512) {
      int c = p & 15, grp = (p >> 4) & 3, kb = p >> 6;
      unsigned short* dst = frag + kb*512 + (grp*16 + c)*8;
      const float* s = Wout + (size_t)(base + c)*H + kb*32 + grp*8;
      #pragma unroll
      for (int j = 0; j < 8; ++j) dst[j] = f2bf(s[j]);
    }
    if (tid < 16) bo[tid] = bout[base + tid];
  }

  unsigned phase = 1;
  bar_worker(ctr, epoch, xcnt, xdone, xcd, phase, tid, bid); ++phase;

  // ---------------- pipelined recurrence ----------------
  for (int s = 0; s < 1026; ++s, ++phase) {
    if (role == 0) {
      if (s < 1024) {
        const int t = s;
        float* G  = (float*)(smem + 98304);
        float* hm = (float*)(smem + 110848);
        float* bi = (float*)(smem + 114944);
        float* bh = (float*)(smem + 115136);
        if (w < 4) {   // waves 0-3: one M-tile each, N=48 (3 tiles), K=1024
          const unsigned short* src  = h0buf + ((t+1)&1)*65536;
          const unsigned short* arow = src + (w*16 + (lane&15))*H + ((lane>>4)*8);
          const unsigned short* bb   = frag + lane*8;
          f32x4 a0 = {0,0,0,0}, a1 = {0,0,0,0}, a2 = {0,0,0,0};
          s16x8 A0[16], A1[16];
          INVL1();
          GLD16A(A0, arow);
          GLD16B(A1, arow);
          WAITV(16); TIE16(A0);
          #pragma unroll
          for (int i = 0; i < 16; ++i) {
            s16x8 b0 = *(const s16x8*)(bb + (i*3+0)*512);
            s16x8 b1 = *(const s16x8*)(bb + (i*3+1)*512);
            s16x8 b2 = *(const s16x8*)(bb + (i*3+2)*512);
            a0 = __builtin_amdgcn_mfma_f32_16x16x32_bf16(A0[i], b0, a0, 0, 0, 0);
            a1 = __builtin_amdgcn_mfma_f32_16x16x32_bf16(A0[i], b1, a1, 0, 0, 0);
            a2 = __builtin_amdgcn_mfma_f32_16x16x32_bf16(A0[i], b2, a2, 0, 0, 0);
          }
          WAITV(0); TIE16(A1);
          #pragma unroll
          for (int i = 0; i < 16; ++i) {
            int kb = 16 + i;
            s16x8 b0 = *(const s16x8*)(bb + (kb*3+0)*512);
            s16x8 b1 = *(const s16x8*)(bb + (kb*3+1)*512);
            s16x8 b2 = *(const s16x8*)(bb + (kb*3+2)*512);
            a0 = __builtin_amdgcn_mfma_f32_16x16x32_bf16(A1[i], b0, a0, 0, 0, 0);
            a1 = __builtin_amdgcn_mfma_f32_16x16x32_bf16(A1[i], b1, a1, 0, 0, 0);
            a2 = __builtin_amdgcn_mfma_f32_16x16x32_bf16(A1[i], b2, a2, 0, 0, 0);
          }
          int col = lane & 15, r0 = (lane >> 4) * 4;
          #pragma unroll
          for (int r = 0; r < 4; ++r) {
            int brow = w*16 + r0 + r;
            G[brow*49 +      col] = a0[r];
            G[brow*49 + 16 + col] = a1[r];
            G[brow*49 + 32 + col] = a2[r];
          }
        }
        __syncthreads();
        if (tid < 128) {
          int b = tid >> 1, u0 = (tid & 1) * 8;
          s16x8 pk;
          #pragma unroll
          for (int j = 0; j < 8; ++j) {
            int u = u0 + j;
            float hr = G[b*49 + u]      + bh[u];
            float hz = G[b*49 + 16 + u] + bh[16 + u];
            float hn = G[b*49 + 32 + u] + bh[32 + u];
            float r  = sigm(bi[u] + hr);         // gx = b_ih_0 (x==0)
            float zg = sigm(bi[16 + u] + hz);
            float n  = tanhf(bi[32 + u] + r * hn);
            int idx = b*16 + u;
            float hp = hm[idx];
            float hv = (1.f - zg) * n + zg * hp;
            hm[idx] = hv;
            pk[j] = (short)f2bf(hv);
          }
          gst16(pk, &h0buf[(t&1)*65536 + b*H + base + u0]);
        }
      }
    } else if (role == 1) {
      if (s >= 1 && s <= 1024) {
        const int t = s - 1;
        float* Gx = (float*)(smem + 131072);
        float* Gh = (float*)(smem + 139520);
        float* hm = (float*)(smem + 147968);
        float* bi = (float*)(smem + 150016);
        float* bh = (float*)(smem + 150112);
        {
          const int mt  = w & 3;
          const int isx = (w < 4);    // waves 0-3: gx GEMM, 4-7: gh GEMM
          const unsigned short* src  = isx ? (h0buf + (t&1)*65536)
                                           : (h1buf + ((t+1)&1)*65536);
          const unsigned short* arow = src + (mt*16 + (lane&15))*H + ((lane>>4)*8);
          const unsigned short* bb   = frag + (isx ? 0 : 32768) + lane*8;
          f32x4 a0 = {0,0,0,0}, a1 = {0,0,0,0};
          s16x8 A0[16], A1[16];
          INVL1();
          GLD16A(A0, arow);
          GLD16B(A1, arow);
          WAITV(16); TIE16(A0);
          #pragma unroll
          for (int i = 0; i < 16; ++i) {
            s16x8 b0 = *(const s16x8*)(bb + (i*2+0)*512);
            s16x8 b1 = *(const s16x8*)(bb + (i*2+1)*512);
            a0 = __builtin_amdgcn_mfma_f32_16x16x32_bf16(A0[i], b0, a0, 0, 0, 0);
            a1 = __builtin_amdgcn_mfma_f32_16x16x32_bf16(A0[i], b1, a1, 0, 0, 0);
          }
          WAITV(0); TIE16(A1);
          #pragma unroll
          for (int i = 0; i < 16; ++i) {
            int kb = 16 + i;
            s16x8 b0 = *(const s16x8*)(bb + (kb*2+0)*512);
            s16x8 b1 = *(const s16x8*)(bb + (kb*2+1)*512);
            a0 = __builtin_amdgcn_mfma_f32_16x16x32_bf16(A1[i], b0, a0, 0, 0, 0);
            a1 = __builtin_amdgcn_mfma_f32_16x16x32_bf16(A1[i], b1, a1, 0, 0, 0);
          }
          float* G = isx ? Gx : Gh;
          int col = lane & 15, r0 = (lane >> 4) * 4;
          #pragma unroll
          for (int r = 0; r < 4; ++r) {
            int brow = mt*16 + r0 + r;
            G[brow*33 +      col] = a0[r];
            G[brow*33 + 16 + col] = a1[r];
          }
        }
        __syncthreads();
        if (tid < 64) {
          int b = tid;
          s16x8 pk;
          #pragma unroll
          for (int u = 0; u < 8; ++u) {
            float xr = Gx[b*33 + u]      + bi[u];
            float xz = Gx[b*33 + 8 + u]  + bi[8 + u];
            float xn = Gx[b*33 + 16 + u] + bi[16 + u];
            float hr = Gh[b*33 + u]      + bh[u];
            float hz = Gh[b*33 + 8 + u]  + bh[8 + u];
            float hn = Gh[b*33 + 16 + u] + bh[16 + u];
            float r  = sigm(xr + hr);
            float zg = sigm(xz + hz);
            float n  = tanhf(xn + r * hn);
            int idx = b*8 + u;
            float hp = hm[idx];
            float hv = (1.f - zg) * n + zg * hp;
            hm[idx] = hv;
            pk[u] = (short)f2bf(hv);
          }
          gst16(pk, &h1buf[(t&1)*65536 + b*H + base]);
        }
      }
    } else {
      if (s >= 2) {
        const int t = s - 2;
        float* bo = (float*)(smem + 32768);
        if (w < 4) {
          const unsigned short* src  = h1buf + (t&1)*65536;
          const unsigned short* arow = src + (w*16 + (lane&15))*H + ((lane>>4)*8);
          const unsigned short* bb   = frag + lane*8;
          f32x4 a0 = {0,0,0,0};
          s16x8 A0[16], A1[16];
          INVL1();
          GLD16A(A0, arow);
          GLD16B(A1, arow);
          WAITV(16); TIE16(A0);
          #pragma unroll
          for (int i = 0; i < 16; ++i) {
            s16x8 b0 = *(const s16x8*)(bb + i*512);
            a0 = __builtin_amdgcn_mfma_f32_16x16x32_bf16(A0[i], b0, a0, 0, 0, 0);
          }
          WAITV(0); TIE16(A1);
          #pragma unroll
          for (int i = 0; i < 16; ++i) {
            s16x8 b0 = *(const s16x8*)(bb + (16+i)*512);
            a0 = __builtin_amdgcn_mfma_f32_16x16x32_bf16(A1[i], b0, a0, 0, 0, 0);
          }
          int col = lane & 15, r0 = (lane >> 4) * 4;
          #pragma unroll
          for (int r = 0; r < 4; ++r) {
            int brow = w*16 + r0 + r;
            gst4(a0[r] + bo[col], out + (size_t)(brow*T + t)*128 + base + col);
          }
        }
      }
    }
    bar_worker(ctr, epoch, xcnt, xdone, xcd, phase, tid, bid);
  }
}

extern "C" void kernel_launch(void* const* d_in, const int* in_sizes, int n_in,
                              void* d_out, int out_size, void* d_ws, size_t ws_size,
                              hipStream_t stream) {
  const float* z    = (const float*)d_in[0];
  // d_in[1] = seq_len (==1024, hard-coded); d_in[2] = W_ih_0 (unused: x0==0)
  const float* Whh0 = (const float*)d_in[3];
  const float* bih0 = (const float*)d_in[4];
  const float* bhh0 = (const float*)d_in[5];
  const float* Wih1 = (const float*)d_in[6];
  const float* Whh1 = (const float*)d_in[7];
  const float* bih1 = (const float*)d_in[8];
  const float* bhh1 = (const float*)d_in[9];
  const float* Wout = (const float*)d_in[10];
  const float* bout = (const float*)d_in[11];
  float* out = (float*)d_out;

  // ws layout: [0,3200) ctr | 4096 epoch | [4224,4736) xdone (8x64B)
  //            [8192,139776) xcnt (1028x8x16B) | 147456 h0buf | 409600 h1buf
  unsigned* ctr   = (unsigned*)d_ws;
  unsigned* epoch = (unsigned*)((char*)d_ws + 4096);
  unsigned* xdone = (unsigned*)((char*)d_ws + 4224);
  unsigned* xcnt  = (unsigned*)((char*)d_ws + 8192);
  unsigned short* h0buf = (unsigned short*)((char*)d_ws + 147456);
  unsigned short* h1buf = (unsigned short*)((char*)d_ws + 147456 + 262144);

  hipFuncSetAttribute((const void*)gru_pipeline,
                      hipFuncAttributeMaxDynamicSharedMemorySize, SMEM_BYTES);
  hipMemsetAsync(d_ws, 0, 147456, stream);   // ctr+epoch+xdone+xcnt

  void* args[] = { (void*)&z, (void*)&Whh0, (void*)&bih0, (void*)&bhh0,
                   (void*)&Wih1, (void*)&Whh1, (void*)&bih1, (void*)&bhh1,
                   (void*)&Wout, (void*)&bout, (void*)&out,
                   (void*)&h0buf, (void*)&h1buf, (void*)&ctr, (void*)&epoch,
                   (void*)&xcnt, (void*)&xdone };
  hipLaunchCooperativeKernel((void*)gru_pipeline, dim3(NBLK), dim3(512),
                             args, SMEM_BYTES, stream);
}

// Round 5
// 13002.892 us; speedup vs baseline: 1.1328x; 1.1328x over previous
//
#include <hip/hip_runtime.h>

// DecoderGRU: 2-layer GRU (B=64, H=1024, T=1024, OUT=128) + output projection.
// R5: 4-stage software pipeline, point-to-point sync (no global barrier).
//   S0 (blk 0-63):   h0^s   = GRU0(h0^{s-1})            [16 units each]
//   S1 (blk 64-127): Gx^t   = y0^t @ W_ih1^T            [t=s-1, 16 units]
//   S2 (blk 128-191): h1^t  = GRU1(Gx^t, h1^{t-1})      [t=s-2, 16 units]
//   S3 (blk 192-199): out^t = y1^t @ W_out^T + b        [t=s-3, 16 cols]
// Per-CU read is TA-line-rate-bound (~8.5 B/cyc/CU, one 64B line / ~7 cyc —
// R3 measurement); R5 halves the critical per-CU bytes (256->~128KB/step).
// h/Gx move via sc0sc1 bypass (IF$-coherent); triple-buffered slots; per-stage
// monotone arrive counters (8 padded lines), consumers poll producers only.

#define NBLK 200
#define SMEM_BYTES 115712
#define H 1024
#define T 1024
#define SLOT(k) (((k) + 3) % 3)

typedef short s16x8 __attribute__((ext_vector_type(8)));
typedef float f32x4 __attribute__((ext_vector_type(4)));

__device__ __forceinline__ unsigned short f2bf(float f) {
  union { float f; unsigned u; } v; v.f = f;
  return (unsigned short)((v.u + 0x7FFFu + ((v.u >> 16) & 1u)) >> 16);
}
__device__ __forceinline__ float sigm(float x) { return 1.f / (1.f + __expf(-x)); }

__device__ __forceinline__ void st_u16(void* p, unsigned short v) {
  __hip_atomic_store((unsigned short*)p, v, __ATOMIC_RELAXED, __HIP_MEMORY_SCOPE_AGENT);
}

// ---- coalesced device-coherent loads/stores (bypass L1/L2 -> IF$) ----
#define GLD(d, p, off) \
  asm volatile("global_load_dwordx4 %0, %1, off offset:" #off " sc0 sc1" \
               : "=v"(d) : "v"(p))
#define GLD16A(A, p) \
  GLD(A[0],p,0);    GLD(A[1],p,64);   GLD(A[2],p,128);  GLD(A[3],p,192);  \
  GLD(A[4],p,256);  GLD(A[5],p,320);  GLD(A[6],p,384);  GLD(A[7],p,448);  \
  GLD(A[8],p,512);  GLD(A[9],p,576);  GLD(A[10],p,640); GLD(A[11],p,704); \
  GLD(A[12],p,768); GLD(A[13],p,832); GLD(A[14],p,896); GLD(A[15],p,960)
#define GLD16B(A, p) \
  GLD(A[0],p,1024); GLD(A[1],p,1088); GLD(A[2],p,1152); GLD(A[3],p,1216); \
  GLD(A[4],p,1280); GLD(A[5],p,1344); GLD(A[6],p,1408); GLD(A[7],p,1472); \
  GLD(A[8],p,1536); GLD(A[9],p,1600); GLD(A[10],p,1664); GLD(A[11],p,1728); \
  GLD(A[12],p,1792); GLD(A[13],p,1856); GLD(A[14],p,1920); GLD(A[15],p,1984)
#define WAITV(n) asm volatile("s_waitcnt vmcnt(" #n ")" ::: "memory")
#define TIE16(A) \
  asm volatile("" : "+v"(A[0]),"+v"(A[1]),"+v"(A[2]),"+v"(A[3]), \
                    "+v"(A[4]),"+v"(A[5]),"+v"(A[6]),"+v"(A[7]), \
                    "+v"(A[8]),"+v"(A[9]),"+v"(A[10]),"+v"(A[11]), \
                    "+v"(A[12]),"+v"(A[13]),"+v"(A[14]),"+v"(A[15]))

__device__ __forceinline__ void gst16(s16x8 v, void* p) {
  asm volatile("global_store_dwordx4 %0, %1, off sc0 sc1" :: "v"(p), "v"(v) : "memory");
}
__device__ __forceinline__ void gst16f(f32x4 v, void* p) {
  asm volatile("global_store_dwordx4 %0, %1, off sc0 sc1" :: "v"(p), "v"(v) : "memory");
}
__device__ __forceinline__ void gst4(float v, void* p) {
  asm volatile("global_store_dword %0, %1, off sc0 sc1" :: "v"(p), "v"(v) : "memory");
}
__device__ __forceinline__ f32x4 gldf(const float* p) {
  f32x4 d;
  asm volatile("global_load_dwordx4 %0, %1, off sc0 sc1" : "=v"(d) : "v"(p));
  return d;
}

// Poll up to 3 producer conditions: stage done through step k (init = step -1
// counts one arrival). Counter layout: cnt[stage*256 + line*32], 8 lines/stage.
// done(stage,k) <=> every line >= perline*(k+2).
__device__ __forceinline__ void waitp(unsigned* cnt, int lane,
                                      int sA, int kA, int pA,
                                      int sB, int kB, int pB,
                                      int sC, int kC, int pC) {
  int j = lane >> 3, line = lane & 7;
  int stg = 0, tgt = 0;
  if (j == 0)      { stg = sA; tgt = pA * (kA + 2); }
  else if (j == 1) { stg = sB; tgt = pB * (kB + 2); }
  else if (j == 2) { stg = sC; tgt = pC * (kC + 2); }
  bool act = (j < 3) && (tgt > 0);
  unsigned* a = cnt + (act ? stg : 0) * 256 + line * 32;
  for (;;) {
    unsigned v = act ? __hip_atomic_load(a, __ATOMIC_RELAXED, __HIP_MEMORY_SCOPE_AGENT) : 0u;
    if (__ballot(act && v < (unsigned)tgt) == 0ull) break;
    __builtin_amdgcn_s_sleep(1);
  }
}

extern "C" __global__ void __launch_bounds__(512, 2)
gru_pipeline(const float* __restrict__ z,
             const float* __restrict__ Whh0,
             const float* __restrict__ bih0, const float* __restrict__ bhh0,
             const float* __restrict__ Wih1, const float* __restrict__ Whh1,
             const float* __restrict__ bih1, const float* __restrict__ bhh1,
             const float* __restrict__ Wout, const float* __restrict__ bout,
             float* __restrict__ out, char* __restrict__ ws)
{
  extern __shared__ char smem[];
  const int tid  = threadIdx.x;
  const int lane = tid & 63;
  const int w    = tid >> 6;
  const int bid  = blockIdx.x;

  unsigned*       cnt = (unsigned*)ws;                        // 4 x 8 x 128B
  unsigned short* h0  = (unsigned short*)(ws + 4096);         // 3 x 64x1024 bf16
  unsigned short* h1  = (unsigned short*)(ws + 397312);       // 3 x 64x1024 bf16
  float*          gxw = (float*)(ws + 790528);                // 3 x 64x64x48 f32

  int role, base;
  if (bid < 64)       { role = 0; base = bid * 16; }
  else if (bid < 128) { role = 1; base = (bid - 64) * 16; }
  else if (bid < 192) { role = 2; base = (bid - 128) * 16; }
  else                { role = 3; base = (bid - 192) * 16; }
  const int ug = base >> 4;

  unsigned short* frag = (unsigned short*)smem;
  float* G  = (float*)(smem + 98304);    // S0/S2: 64x49; S1: Gtmp 64x48
  float* hm = (float*)(smem + 110848);   // S0/S2: fp32 master state
  float* bi = (float*)(smem + 114944);
  float* bh = (float*)(smem + 115136);
  float* bo = (float*)(smem + 32768);    // S3 only

  // ---------------- init: weights -> LDS bf16 B-fragments, state prefill ----
  if (role == 0 || role == 1 || role == 2) {
    const float* W = (role == 0) ? Whh0 : (role == 1) ? Wih1 : Whh1;
    for (int p = tid; p < 6144; p += 512) {
      int c = p % 48; int r2 = p / 48; int grp = r2 & 3; int kb = r2 >> 2;
      int g = c >> 4, u = c & 15;
      unsigned short* dst = frag + (kb*3 + g)*512 + (grp*16 + u)*8;
      const float* s = W + (size_t)(g*H + base + u)*H + kb*32 + grp*8;
      #pragma unroll
      for (int j = 0; j < 8; ++j) dst[j] = f2bf(s[j]);
    }
  }
  if (role == 0) {
    if (tid < 48) {
      int g = tid >> 4, u = tid & 15;
      bi[tid] = bih0[g*H + base + u];
      bh[tid] = bhh0[g*H + base + u];
    }
    for (int p = tid; p < 1024; p += 512) {
      int b = p >> 4, u = p & 15;
      float v = z[b*H + base + u];
      hm[p] = v;
      st_u16(&h0[2*65536 + b*H + base + u], f2bf(v));   // h0^{-1} := z (slot 2)
    }
  } else if (role == 2) {
    if (tid < 48) {
      int g = tid >> 4, u = tid & 15;
      bi[tid] = bih1[g*H + base + u];
      bh[tid] = bhh1[g*H + base + u];
    }
    for (int p = tid; p < 1024; p += 512) {
      int b = p >> 4, u = p & 15;
      float v = z[b*H + base + u];
      hm[p] = v;
      st_u16(&h1[2*65536 + b*H + base + u], f2bf(v));   // h1^{-1} := z (slot 2)
    }
  } else if (role == 3) {
    for (int p = tid; p < 2048; p += 512) {
      int c = p & 15, grp = (p >> 4) & 3, kb = p >> 6;
      unsigned short* dst = frag + kb*512 + (grp*16 + c)*8;
      const float* s = Wout + (size_t)(base + c)*H + kb*32 + grp*8;
      #pragma unroll
      for (int j = 0; j < 8; ++j) dst[j] = f2bf(s[j]);
    }
    if (tid < 16) bo[tid] = bout[base + tid];
  }

  // init arrival (counts as step -1)
  WAITV(0);
  __syncthreads();
  if (tid == 0)
    __hip_atomic_fetch_add(cnt + role*256 + (bid & 7)*32, 1u,
                           __ATOMIC_RELAXED, __HIP_MEMORY_SCOPE_AGENT);

  // ---------------- pipelined recurrence: 1027 super-steps ----------------
  for (int s = 0; s < 1027; ++s) {
    // ---- wait on producers (wave 0 polls, then block syncs) ----
    if (w == 0) {
      if (role == 0)      waitp(cnt, lane, 0, s-1, 8,  1, s-2, 8,  0, -5, 0);
      else if (role == 1) waitp(cnt, lane, 0, s-1, 8,  2, s-2, 8,  0, -5, 0);
      else if (role == 2) waitp(cnt, lane, 2, s-1, 8,  1, s-1, 8,  3, s-2, 1);
      else                waitp(cnt, lane, 2, s-1, 8,  0, -5, 0,  0, -5, 0);
    }
    __syncthreads();

    if (role == 0 && s < 1024) {
      // ---- S0: h0^s from h0^{s-1} ----
      if (w < 4) {
        const unsigned short* src  = h0 + SLOT(s-1)*65536;
        const unsigned short* arow = src + (w*16 + (lane&15))*H + ((lane>>4)*8);
        const unsigned short* bb   = frag + lane*8;
        f32x4 a0 = {0,0,0,0}, a1 = {0,0,0,0}, a2 = {0,0,0,0};
        s16x8 A0[16], A1[16];
        GLD16A(A0, arow); GLD16B(A1, arow);
        WAITV(16); TIE16(A0);
        #pragma unroll
        for (int i = 0; i < 16; ++i) {
          s16x8 b0 = *(const s16x8*)(bb + (i*3+0)*512);
          s16x8 b1 = *(const s16x8*)(bb + (i*3+1)*512);
          s16x8 b2 = *(const s16x8*)(bb + (i*3+2)*512);
          a0 = __builtin_amdgcn_mfma_f32_16x16x32_bf16(A0[i], b0, a0, 0, 0, 0);
          a1 = __builtin_amdgcn_mfma_f32_16x16x32_bf16(A0[i], b1, a1, 0, 0, 0);
          a2 = __builtin_amdgcn_mfma_f32_16x16x32_bf16(A0[i], b2, a2, 0, 0, 0);
        }
        WAITV(0); TIE16(A1);
        #pragma unroll
        for (int i = 0; i < 16; ++i) {
          int kb = 16 + i;
          s16x8 b0 = *(const s16x8*)(bb + (kb*3+0)*512);
          s16x8 b1 = *(const s16x8*)(bb + (kb*3+1)*512);
          s16x8 b2 = *(const s16x8*)(bb + (kb*3+2)*512);
          a0 = __builtin_amdgcn_mfma_f32_16x16x32_bf16(A1[i], b0, a0, 0, 0, 0);
          a1 = __builtin_amdgcn_mfma_f32_16x16x32_bf16(A1[i], b1, a1, 0, 0, 0);
          a2 = __builtin_amdgcn_mfma_f32_16x16x32_bf16(A1[i], b2, a2, 0, 0, 0);
        }
        int col = lane & 15, r0 = (lane >> 4) * 4;
        #pragma unroll
        for (int r = 0; r < 4; ++r) {
          int brow = w*16 + r0 + r;
          G[brow*49 +      col] = a0[r];
          G[brow*49 + 16 + col] = a1[r];
          G[brow*49 + 32 + col] = a2[r];
        }
      }
      __syncthreads();
      if (tid < 128) {
        int b = tid >> 1, u0 = (tid & 1) * 8;
        s16x8 pk;
        #pragma unroll
        for (int j = 0; j < 8; ++j) {
          int u = u0 + j;
          float hr = G[b*49 + u]      + bh[u];
          float hz = G[b*49 + 16 + u] + bh[16 + u];
          float hn = G[b*49 + 32 + u] + bh[32 + u];
          float r  = sigm(bi[u] + hr);         // gx = b_ih_0 (x==0)
          float zg = sigm(bi[16 + u] + hz);
          float n  = tanhf(bi[32 + u] + r * hn);
          int idx = b*16 + u;
          float hp = hm[idx];
          float hv = (1.f - zg) * n + zg * hp;
          hm[idx] = hv;
          pk[j] = (short)f2bf(hv);
        }
        gst16(pk, &h0[SLOT(s)*65536 + b*H + base + u0]);
      }
    } else if (role == 1 && s >= 1 && s <= 1024) {
      // ---- S1: Gx^t = y0^t @ W_ih1^T, t = s-1 ----
      const int t = s - 1;
      if (w < 4) {
        const unsigned short* src  = h0 + SLOT(t)*65536;
        const unsigned short* arow = src + (w*16 + (lane&15))*H + ((lane>>4)*8);
        const unsigned short* bb   = frag + lane*8;
        f32x4 a0 = {0,0,0,0}, a1 = {0,0,0,0}, a2 = {0,0,0,0};
        s16x8 A0[16], A1[16];
        GLD16A(A0, arow); GLD16B(A1, arow);
        WAITV(16); TIE16(A0);
        #pragma unroll
        for (int i = 0; i < 16; ++i) {
          s16x8 b0 = *(const s16x8*)(bb + (i*3+0)*512);
          s16x8 b1 = *(const s16x8*)(bb + (i*3+1)*512);
          s16x8 b2 = *(const s16x8*)(bb + (i*3+2)*512);
          a0 = __builtin_amdgcn_mfma_f32_16x16x32_bf16(A0[i], b0, a0, 0, 0, 0);
          a1 = __builtin_amdgcn_mfma_f32_16x16x32_bf16(A0[i], b1, a1, 0, 0, 0);
          a2 = __builtin_amdgcn_mfma_f32_16x16x32_bf16(A0[i], b2, a2, 0, 0, 0);
        }
        WAITV(0); TIE16(A1);
        #pragma unroll
        for (int i = 0; i < 16; ++i) {
          int kb = 16 + i;
          s16x8 b0 = *(const s16x8*)(bb + (kb*3+0)*512);
          s16x8 b1 = *(const s16x8*)(bb + (kb*3+1)*512);
          s16x8 b2 = *(const s16x8*)(bb + (kb*3+2)*512);
          a0 = __builtin_amdgcn_mfma_f32_16x16x32_bf16(A1[i], b0, a0, 0, 0, 0);
          a1 = __builtin_amdgcn_mfma_f32_16x16x32_bf16(A1[i], b1, a1, 0, 0, 0);
          a2 = __builtin_amdgcn_mfma_f32_16x16x32_bf16(A1[i], b2, a2, 0, 0, 0);
        }
        int col = lane & 15, r0 = (lane >> 4) * 4;
        #pragma unroll
        for (int r = 0; r < 4; ++r) {
          int brow = w*16 + r0 + r;
          G[brow*48 +      col] = a0[r];
          G[brow*48 + 16 + col] = a1[r];
          G[brow*48 + 32 + col] = a2[r];
        }
      }
      __syncthreads();
      {
        float* dst = gxw + (size_t)SLOT(t)*196608 + ug*3072;
        for (int c2 = tid; c2 < 768; c2 += 512) {
          int b = c2 / 12, k = c2 % 12;
          f32x4 v = *(f32x4*)(G + b*48 + k*4);
          gst16f(v, dst + b*48 + k*4);
        }
      }
    } else if (role == 2 && s >= 2 && s <= 1025) {
      // ---- S2: h1^t from Gx^t and h1^{t-1}, t = s-2 ----
      const int t = s - 2;
      f32x4 g0, g1, g2, g3, g4, g5;
      int b_ew = tid >> 1, u0 = (tid & 1) * 8;
      if (tid < 128) {   // preload Gx partials (issued before A-loads)
        const float* gxp = gxw + (size_t)SLOT(t)*196608 + ug*3072 + b_ew*48 + u0;
        g0 = gldf(gxp);      g1 = gldf(gxp + 4);
        g2 = gldf(gxp + 16); g3 = gldf(gxp + 20);
        g4 = gldf(gxp + 32); g5 = gldf(gxp + 36);
      }
      if (w < 4) {
        const unsigned short* src  = h1 + SLOT(t-1)*65536;
        const unsigned short* arow = src + (w*16 + (lane&15))*H + ((lane>>4)*8);
        const unsigned short* bb   = frag + lane*8;
        f32x4 a0 = {0,0,0,0}, a1 = {0,0,0,0}, a2 = {0,0,0,0};
        s16x8 A0[16], A1[16];
        GLD16A(A0, arow); GLD16B(A1, arow);
        WAITV(16); TIE16(A0);   // also drains the (older) Gx preloads
        #pragma unroll
        for (int i = 0; i < 16; ++i) {
          s16x8 b0 = *(const s16x8*)(bb + (i*3+0)*512);
          s16x8 b1 = *(const s16x8*)(bb + (i*3+1)*512);
          s16x8 b2 = *(const s16x8*)(bb + (i*3+2)*512);
          a0 = __builtin_amdgcn_mfma_f32_16x16x32_bf16(A0[i], b0, a0, 0, 0, 0);
          a1 = __builtin_amdgcn_mfma_f32_16x16x32_bf16(A0[i], b1, a1, 0, 0, 0);
          a2 = __builtin_amdgcn_mfma_f32_16x16x32_bf16(A0[i], b2, a2, 0, 0, 0);
        }
        WAITV(0); TIE16(A1);
        #pragma unroll
        for (int i = 0; i < 16; ++i) {
          int kb = 16 + i;
          s16x8 b0 = *(const s16x8*)(bb + (kb*3+0)*512);
          s16x8 b1 = *(const s16x8*)(bb + (kb*3+1)*512);
          s16x8 b2 = *(const s16x8*)(bb + (kb*3+2)*512);
          a0 = __builtin_amdgcn_mfma_f32_16x16x32_bf16(A1[i], b0, a0, 0, 0, 0);
          a1 = __builtin_amdgcn_mfma_f32_16x16x32_bf16(A1[i], b1, a1, 0, 0, 0);
          a2 = __builtin_amdgcn_mfma_f32_16x16x32_bf16(A1[i], b2, a2, 0, 0, 0);
        }
        int col = lane & 15, r0 = (lane >> 4) * 4;
        #pragma unroll
        for (int r = 0; r < 4; ++r) {
          int brow = w*16 + r0 + r;
          G[brow*49 +      col] = a0[r];
          G[brow*49 + 16 + col] = a1[r];
          G[brow*49 + 32 + col] = a2[r];
        }
      }
      WAITV(0);
      __syncthreads();
      if (tid < 128) {
        int b = b_ew;
        s16x8 pk;
        #pragma unroll
        for (int j = 0; j < 8; ++j) {
          int u = u0 + j;
          float xr = (j < 4 ? g0[j] : g1[j-4]) + bi[u];
          float xz = (j < 4 ? g2[j] : g3[j-4]) + bi[16 + u];
          float xn = (j < 4 ? g4[j] : g5[j-4]) + bi[32 + u];
          float hr = G[b*49 + u]      + bh[u];
          float hz = G[b*49 + 16 + u] + bh[16 + u];
          float hn = G[b*49 + 32 + u] + bh[32 + u];
          float r  = sigm(xr + hr);
          float zg = sigm(xz + hz);
          float n  = tanhf(xn + r * hn);
          int idx = b*16 + u;
          float hp = hm[idx];
          float hv = (1.f - zg) * n + zg * hp;
          hm[idx] = hv;
          pk[j] = (short)f2bf(hv);
        }
        gst16(pk, &h1[SLOT(t)*65536 + b*H + base + u0]);
      }
    } else if (role == 3 && s >= 3) {
      // ---- S3: out^t = y1^t @ W_out^T + b, t = s-3 ----
      const int t = s - 3;
      if (w < 4) {
        const unsigned short* src  = h1 + SLOT(t)*65536;
        const unsigned short* arow = src + (w*16 + (lane&15))*H + ((lane>>4)*8);
        const unsigned short* bb   = frag + lane*8;
        f32x4 a0 = {0,0,0,0};
        s16x8 A0[16], A1[16];
        GLD16A(A0, arow); GLD16B(A1, arow);
        WAITV(16); TIE16(A0);
        #pragma unroll
        for (int i = 0; i < 16; ++i) {
          s16x8 b0 = *(const s16x8*)(bb + i*512);
          a0 = __builtin_amdgcn_mfma_f32_16x16x32_bf16(A0[i], b0, a0, 0, 0, 0);
        }
        WAITV(0); TIE16(A1);
        #pragma unroll
        for (int i = 0; i < 16; ++i) {
          s16x8 b0 = *(const s16x8*)(bb + (16+i)*512);
          a0 = __builtin_amdgcn_mfma_f32_16x16x32_bf16(A1[i], b0, a0, 0, 0, 0);
        }
        int col = lane & 15, r0 = (lane >> 4) * 4;
        #pragma unroll
        for (int r = 0; r < 4; ++r) {
          int brow = w*16 + r0 + r;
          gst4(a0[r] + bo[col], out + (size_t)(brow*T + t)*128 + base + col);
        }
      }
    }

    // ---- arrive ----
    WAITV(0);
    __syncthreads();
    if (tid == 0)
      __hip_atomic_fetch_add(cnt + role*256 + (bid & 7)*32, 1u,
                             __ATOMIC_RELAXED, __HIP_MEMORY_SCOPE_AGENT);
  }
}

extern "C" void kernel_launch(void* const* d_in, const int* in_sizes, int n_in,
                              void* d_out, int out_size, void* d_ws, size_t ws_size,
                              hipStream_t stream) {
  const float* z    = (const float*)d_in[0];
  // d_in[1] = seq_len (==1024, hard-coded); d_in[2] = W_ih_0 (unused: x0==0)
  const float* Whh0 = (const float*)d_in[3];
  const float* bih0 = (const float*)d_in[4];
  const float* bhh0 = (const float*)d_in[5];
  const float* Wih1 = (const float*)d_in[6];
  const float* Whh1 = (const float*)d_in[7];
  const float* bih1 = (const float*)d_in[8];
  const float* bhh1 = (const float*)d_in[9];
  const float* Wout = (const float*)d_in[10];
  const float* bout = (const float*)d_in[11];
  float* out = (float*)d_out;
  char* ws = (char*)d_ws;

  hipFuncSetAttribute((const void*)gru_pipeline,
                      hipFuncAttributeMaxDynamicSharedMemorySize, SMEM_BYTES);
  hipMemsetAsync(d_ws, 0, 4096, stream);   // arrive counters

  void* args[] = { (void*)&z, (void*)&Whh0, (void*)&bih0, (void*)&bhh0,
                   (void*)&Wih1, (void*)&Whh1, (void*)&bih1, (void*)&bhh1,
                   (void*)&Wout, (void*)&bout, (void*)&out, (void*)&ws };
  hipLaunchCooperativeKernel((void*)gru_pipeline, dim3(NBLK), dim3(512),
                             args, SMEM_BYTES, stream);
}

// Round 7
// 12261.295 us; speedup vs baseline: 1.2014x; 1.0605x over previous
//
#include <hip/hip_runtime.h>

// DecoderGRU: 2-layer GRU (B=64, H=1024, T=1024, OUT=128) + output projection.
// R7 = R6 (self-timed dataflow pipeline) + race fix.
//   S0 (blk 0-63):   h0^t = GRU0(h0^{t-1})       [16 units/blk]
//   S1 (blk 64-127): Gx^t = y0^t @ W_ih1^T       [16 units/blk]
//   S2 (blk 128-191): h1^t = GRU1(Gx^t, h1^{t-1})[16 units/blk]
//   S3 (blk 192-199): out^t = y1^t @ W_out^T + b [16 cols/blk]
// R6 BUG: S2's Gx preload (inline-asm gldf) was consumed after __syncthreads
// with no vmcnt wait — the compiler does not track asm loads, so it emits
// neither a pre-barrier drain nor a pre-use waitcnt for them. Fix: explicit
// WAITV(0) + register tie right after the preload. All other asm loads were
// already protected by WAITV(n)+TIE pairs inside gemm48.
// Per-block monotone flag (4B, single sc1 store, no RMW). Wave 7 polls
// producer flags (64-lane coalesced) and publishes per-unit-group readiness
// into LDS; GEMM waves spin on LDS (ds_read, vmcnt untouched) and pipeline
// 4-load chunks with WAITV(4)+MFMA. 3 slots/buffer; waits reference strictly
// smaller data-steps -> acyclic.

#define NBLK 200
#define SMEM_BYTES 115392
#define H 1024
#define T 1024
#define SLOT(k) (((k) + 3) % 3)

typedef short s16x8 __attribute__((ext_vector_type(8)));
typedef float f32x4 __attribute__((ext_vector_type(4)));

__device__ __forceinline__ unsigned short f2bf(float f) {
  union { float f; unsigned u; } v; v.f = f;
  return (unsigned short)((v.u + 0x7FFFu + ((v.u >> 16) & 1u)) >> 16);
}
__device__ __forceinline__ float sigm(float x) { return 1.f / (1.f + __expf(-x)); }

__device__ __forceinline__ void st_u16(void* p, unsigned short v) {
  __hip_atomic_store((unsigned short*)p, v, __ATOMIC_RELAXED, __HIP_MEMORY_SCOPE_AGENT);
}
__device__ __forceinline__ void st_i32(int* p, int v) {
  __hip_atomic_store(p, v, __ATOMIC_RELAXED, __HIP_MEMORY_SCOPE_AGENT);
}
__device__ __forceinline__ int ld_i32(const int* p) {
  return __hip_atomic_load(p, __ATOMIC_RELAXED, __HIP_MEMORY_SCOPE_AGENT);
}

// ---- coalesced device-coherent loads/stores (bypass L1/L2 -> coherent pt) --
#define GLD(d, p, off) \
  asm volatile("global_load_dwordx4 %0, %1, off offset:" #off " sc0 sc1" \
               : "=v"(d) : "v"(p))
#define GLDG(A, p) GLD(A[0],p,0); GLD(A[1],p,64); GLD(A[2],p,128); GLD(A[3],p,192)
#define WAITV(n) asm volatile("s_waitcnt vmcnt(" #n ")" ::: "memory")
#define TIE4(A) \
  asm volatile("" : "+v"(A[0]),"+v"(A[1]),"+v"(A[2]),"+v"(A[3]))

__device__ __forceinline__ void gst16(s16x8 v, void* p) {
  asm volatile("global_store_dwordx4 %0, %1, off sc0 sc1" :: "v"(p), "v"(v) : "memory");
}
__device__ __forceinline__ void gst16f(f32x4 v, void* p) {
  asm volatile("global_store_dwordx4 %0, %1, off sc0 sc1" :: "v"(p), "v"(v) : "memory");
}
__device__ __forceinline__ void gst4(float v, void* p) {
  asm volatile("global_store_dword %0, %1, off sc0 sc1" :: "v"(p), "v"(v) : "memory");
}
__device__ __forceinline__ f32x4 gldf(const float* p) {
  f32x4 d;
  asm volatile("global_load_dwordx4 %0, %1, off sc0 sc1" : "=v"(d) : "v"(p));
  return d;
}

// Wave-7 poller: (1) data stage: 64 flags, publish ready[g]=t per 8-flag
// group as it completes; (2) optional single gx flag -> ready[8]; (3)
// optional anti-dep set (just wait). Converged ballot loops.
__device__ __forceinline__ void poller(const int* fd, int dtgt,
                                       const int* fgx, int gtgt,
                                       const int* fa, int na, int atgt,
                                       volatile int* ready, int t, int lane) {
  {
    const int* fp = fd + lane;
    for (;;) {
      int v = ld_i32(fp);
      unsigned long long m = __ballot(v >= dtgt);
      if (lane < 8 && ((m >> (8 * lane)) & 0xFFull) == 0xFFull) ready[lane] = t;
      if (m == ~0ull) break;
      __builtin_amdgcn_s_sleep(1);
    }
  }
  if (fgx) {
    for (;;) {
      int v = (lane == 0) ? ld_i32(fgx) : 0x7fffffff;
      if (__ballot(v < gtgt) == 0ull) break;
      __builtin_amdgcn_s_sleep(1);
    }
    if (lane == 0) ready[8] = t;
  }
  if (fa) {
    bool act = lane < na;
    const int* fp = fa + (act ? lane : 0);
    for (;;) {
      int v = act ? ld_i32(fp) : atgt;
      if (__ballot(v < atgt) == 0ull) break;
      __builtin_amdgcn_s_sleep(1);
    }
  }
}

#define MF3(Ap, g) { \
  _Pragma("unroll") \
  for (int i = 0; i < 4; ++i) { int kb = (g)*4 + i; \
    s16x8 b0 = *(const s16x8*)(bb + (kb*3+0)*512); \
    s16x8 b1 = *(const s16x8*)(bb + (kb*3+1)*512); \
    s16x8 b2 = *(const s16x8*)(bb + (kb*3+2)*512); \
    a0 = __builtin_amdgcn_mfma_f32_16x16x32_bf16(Ap[i], b0, a0, 0, 0, 0); \
    a1 = __builtin_amdgcn_mfma_f32_16x16x32_bf16(Ap[i], b1, a1, 0, 0, 0); \
    a2 = __builtin_amdgcn_mfma_f32_16x16x32_bf16(Ap[i], b2, a2, 0, 0, 0); } }

#define MF1(Ap, g) { \
  _Pragma("unroll") \
  for (int i = 0; i < 4; ++i) { int kb = (g)*4 + i; \
    s16x8 b0 = *(const s16x8*)(bb + kb*512); \
    a0 = __builtin_amdgcn_mfma_f32_16x16x32_bf16(Ap[i], b0, a0, 0, 0, 0); } }

// N=48 GEMM, group-pipelined: spin ready[g] (LDS), GLDG(4), WAITV(4), MFMA.
__device__ __forceinline__ void gemm48(const unsigned short* arow,
                                       const unsigned short* bb,
                                       volatile int* ready, int t,
                                       float* G, int ldg, int lane, int w) {
  f32x4 a0 = {0,0,0,0}, a1 = {0,0,0,0}, a2 = {0,0,0,0};
  s16x8 A0[4], A1[4];
  while (ready[0] < t) __builtin_amdgcn_s_sleep(1);
  GLDG(A0, arow);
  while (ready[1] < t) __builtin_amdgcn_s_sleep(1);
  GLDG(A1, arow + 128);
  #pragma unroll
  for (int g2 = 1; g2 < 4; ++g2) {
    WAITV(4); TIE4(A0); MF3(A0, 2*g2 - 2);
    while (ready[2*g2] < t) __builtin_amdgcn_s_sleep(1);
    GLDG(A0, arow + g2*256);
    WAITV(4); TIE4(A1); MF3(A1, 2*g2 - 1);
    while (ready[2*g2 + 1] < t) __builtin_amdgcn_s_sleep(1);
    GLDG(A1, arow + g2*256 + 128);
  }
  WAITV(4); TIE4(A0); MF3(A0, 6);
  WAITV(0); TIE4(A1); MF3(A1, 7);
  int col = lane & 15, r0 = (lane >> 4) * 4;
  #pragma unroll
  for (int r = 0; r < 4; ++r) {
    int brow = w*16 + r0 + r;
    G[brow*ldg +      col] = a0[r];
    G[brow*ldg + 16 + col] = a1[r];
    G[brow*ldg + 32 + col] = a2[r];
  }
}

extern "C" __global__ void __launch_bounds__(512, 2)
gru_pipeline(const float* __restrict__ z,
             const float* __restrict__ Whh0,
             const float* __restrict__ bih0, const float* __restrict__ bhh0,
             const float* __restrict__ Wih1, const float* __restrict__ Whh1,
             const float* __restrict__ bih1, const float* __restrict__ bhh1,
             const float* __restrict__ Wout, const float* __restrict__ bout,
             float* __restrict__ out, char* __restrict__ ws)
{
  extern __shared__ char smem[];
  const int tid  = threadIdx.x;
  const int lane = tid & 63;
  const int w    = tid >> 6;
  const int bid  = blockIdx.x;

  int*            flags = (int*)ws;                     // [4][64] packed
  unsigned short* h0    = (unsigned short*)(ws + 4096); // 3 x 64x1024 bf16
  unsigned short* h1    = (unsigned short*)(ws + 397312);
  float*          gxw   = (float*)(ws + 790528);        // 3 x 64x(64x48) f32

  int role, p;
  if (bid < 64)       { role = 0; p = bid; }
  else if (bid < 128) { role = 1; p = bid - 64; }
  else if (bid < 192) { role = 2; p = bid - 128; }
  else                { role = 3; p = bid - 192; }
  const int base = p * 16;

  unsigned short* frag = (unsigned short*)smem;
  float* G  = (float*)(smem + 98304);
  float* hm = (float*)(smem + 110848);
  float* bi = (float*)(smem + 114944);
  float* bh = (float*)(smem + 115136);
  float* bo = (float*)(smem + 32768);          // S3 only (past its 32KB frags)
  volatile int* ready = (volatile int*)(smem + 115328);  // [9]

  int* fS0 = flags;      int* fS1 = flags + 64;
  int* fS2 = flags + 128; int* fS3 = flags + 192;

  // ---------------- init: weights -> LDS bf16 B-fragments, prefill ----------
  if (tid < 9) ready[tid] = -1;
  if (role < 3) {
    const float* W = (role == 0) ? Whh0 : (role == 1) ? Wih1 : Whh1;
    for (int q = tid; q < 6144; q += 512) {
      int c = q % 48; int r2 = q / 48; int grp = r2 & 3; int kb = r2 >> 2;
      int g = c >> 4, u = c & 15;
      unsigned short* dst = frag + (kb*3 + g)*512 + (grp*16 + u)*8;
      const float* s = W + (size_t)(g*H + base + u)*H + kb*32 + grp*8;
      #pragma unroll
      for (int j = 0; j < 8; ++j) dst[j] = f2bf(s[j]);
    }
  }
  if (role == 0 || role == 2) {
    const float* bip = (role == 0) ? bih0 : bih1;
    const float* bhp = (role == 0) ? bhh0 : bhh1;
    if (tid < 48) {
      int g = tid >> 4, u = tid & 15;
      bi[tid] = bip[g*H + base + u];
      bh[tid] = bhp[g*H + base + u];
    }
    unsigned short* hb = (role == 0) ? h0 : h1;
    for (int q = tid; q < 1024; q += 512) {
      int b = q >> 4, u = q & 15;
      float v = z[b*H + base + u];
      hm[q] = v;
      st_u16(&hb[2*65536 + b*H + base + u], f2bf(v));   // h^{-1} in slot 2
    }
  } else if (role == 3) {
    for (int q = tid; q < 2048; q += 512) {
      int c = q & 15, grp = (q >> 4) & 3, kb = q >> 6;
      unsigned short* dst = frag + kb*512 + (grp*16 + c)*8;
      const float* s = Wout + (size_t)(base + c)*H + kb*32 + grp*8;
      #pragma unroll
      for (int j = 0; j < 8; ++j) dst[j] = f2bf(s[j]);
    }
    if (tid < 16) bo[tid] = bout[base + tid];
  }
  WAITV(0);
  __syncthreads();
  if (tid == 0) st_i32(&flags[role*64 + p], 1);   // data-step -1 done

  // ---------------- self-timed loops: each role runs t = 0..1023 -----------
  if (role == 0) {
    for (int t = 0; t < 1024; ++t) {
      if (w == 7) {
        poller(fS0, t+1, nullptr, 0, fS1, 64, t-1, ready, t, lane);
      } else if (w < 4) {
        const unsigned short* arow = h0 + SLOT(t-1)*65536
                                     + (w*16 + (lane&15))*H + ((lane>>4)*8);
        gemm48(arow, frag + lane*8, ready, t, G, 49, lane, w);
      }
      __syncthreads();                       // B1: G ready, anti-dep ok
      if (tid < 128) {
        int b = tid >> 1, u0 = (tid & 1) * 8;
        s16x8 pk;
        #pragma unroll
        for (int j = 0; j < 8; ++j) {
          int u = u0 + j;
          float hr = G[b*49 + u]      + bh[u];
          float hz = G[b*49 + 16 + u] + bh[16 + u];
          float hn = G[b*49 + 32 + u] + bh[32 + u];
          float r  = sigm(bi[u] + hr);       // gx = b_ih_0 (x == 0)
          float zg = sigm(bi[16 + u] + hz);
          float n  = tanhf(bi[32 + u] + r * hn);
          int idx = b*16 + u;
          float hp = hm[idx];
          float hv = (1.f - zg) * n + zg * hp;
          hm[idx] = hv;
          pk[j] = (short)f2bf(hv);
        }
        gst16(pk, &h0[SLOT(t)*65536 + b*H + base + u0]);
      }
      WAITV(0);
      __syncthreads();                       // B2: stores drained block-wide
      if (tid == 0) st_i32(&fS0[p], t + 2);
    }
  } else if (role == 1) {
    for (int t = 0; t < 1024; ++t) {
      if (w == 7) {
        poller(fS0, t+2, nullptr, 0, fS2, 64, t-1, ready, t, lane);
      } else if (w < 4) {
        const unsigned short* arow = h0 + SLOT(t)*65536
                                     + (w*16 + (lane&15))*H + ((lane>>4)*8);
        gemm48(arow, frag + lane*8, ready, t, G, 48, lane, w);
      }
      __syncthreads();                       // B1
      {
        float* dst = gxw + (size_t)(t % 3)*196608 + p*3072;
        for (int c2 = tid; c2 < 768; c2 += 512) {
          int b = c2 / 12, k = c2 % 12;
          gst16f(*(f32x4*)(G + b*48 + k*4), dst + b*48 + k*4);
        }
      }
      WAITV(0);
      __syncthreads();                       // B2
      if (tid == 0) st_i32(&fS1[p], t + 2);
    }
  } else if (role == 2) {
    for (int t = 0; t < 1024; ++t) {
      f32x4 g0, g1, g2, g3, g4, g5;
      if (w == 7) {
        poller(fS2, t+1, &fS1[p], t+2, fS3, 8, t-1, ready, t, lane);
      } else if (w < 4) {
        const unsigned short* arow = h1 + SLOT(t-1)*65536
                                     + (w*16 + (lane&15))*H + ((lane>>4)*8);
        gemm48(arow, frag + lane*8, ready, t, G, 49, lane, w);
        if (w < 2) {                         // Gx preload
          while (ready[8] < t) __builtin_amdgcn_s_sleep(1);
          const float* gxp = gxw + (size_t)(t % 3)*196608 + p*3072
                             + (tid >> 1)*48 + (tid & 1)*8;
          g0 = gldf(gxp);      g1 = gldf(gxp + 4);
          g2 = gldf(gxp + 16); g3 = gldf(gxp + 20);
          g4 = gldf(gxp + 32); g5 = gldf(gxp + 36);
          // R7 FIX: asm loads are invisible to the compiler's waitcnt
          // insertion — drain them explicitly before the barrier, and tie
          // the registers so uses can't be scheduled before the wait.
          WAITV(0);
          asm volatile("" : "+v"(g0), "+v"(g1), "+v"(g2),
                            "+v"(g3), "+v"(g4), "+v"(g5));
        }
      }
      __syncthreads();                       // B1: G + Gx regs + anti-dep ok
      if (tid < 128) {
        int b = tid >> 1, u0 = (tid & 1) * 8;
        s16x8 pk;
        #pragma unroll
        for (int j = 0; j < 8; ++j) {
          int u = u0 + j;
          float xr = (j < 4 ? g0[j] : g1[j-4]) + bi[u];
          float xz = (j < 4 ? g2[j] : g3[j-4]) + bi[16 + u];
          float xn = (j < 4 ? g4[j] : g5[j-4]) + bi[32 + u];
          float hr = G[b*49 + u]      + bh[u];
          float hz = G[b*49 + 16 + u] + bh[16 + u];
          float hn = G[b*49 + 32 + u] + bh[32 + u];
          float r  = sigm(xr + hr);
          float zg = sigm(xz + hz);
          float n  = tanhf(xn + r * hn);
          int idx = b*16 + u;
          float hp = hm[idx];
          float hv = (1.f - zg) * n + zg * hp;
          hm[idx] = hv;
          pk[j] = (short)f2bf(hv);
        }
        gst16(pk, &h1[(t % 3)*65536 + b*H + base + u0]);
      }
      WAITV(0);
      __syncthreads();                       // B2
      if (tid == 0) st_i32(&fS2[p], t + 2);
    }
  } else {
    for (int t = 0; t < 1024; ++t) {
      if (w == 7) {
        poller(fS2, t+2, nullptr, 0, nullptr, 0, 0, ready, t, lane);
      } else if (w < 4) {
        const unsigned short* arow = h1 + (t % 3)*65536
                                     + (w*16 + (lane&15))*H + ((lane>>4)*8);
        const unsigned short* bb = frag + lane*8;
        f32x4 a0 = {0,0,0,0};
        s16x8 A0[4], A1[4];
        while (ready[0] < t) __builtin_amdgcn_s_sleep(1);
        GLDG(A0, arow);
        while (ready[1] < t) __builtin_amdgcn_s_sleep(1);
        GLDG(A1, arow + 128);
        #pragma unroll
        for (int g2i = 1; g2i < 4; ++g2i) {
          WAITV(4); TIE4(A0); MF1(A0, 2*g2i - 2);
          while (ready[2*g2i] < t) __builtin_amdgcn_s_sleep(1);
          GLDG(A0, arow + g2i*256);
          WAITV(4); TIE4(A1); MF1(A1, 2*g2i - 1);
          while (ready[2*g2i + 1] < t) __builtin_amdgcn_s_sleep(1);
          GLDG(A1, arow + g2i*256 + 128);
        }
        WAITV(4); TIE4(A0); MF1(A0, 6);
        WAITV(0); TIE4(A1); MF1(A1, 7);
        int col = lane & 15, r0 = (lane >> 4) * 4;
        #pragma unroll
        for (int r = 0; r < 4; ++r) {
          int brow = w*16 + r0 + r;
          gst4(a0[r] + bo[col], out + (size_t)(brow*T + t)*128 + base + col);
        }
      }
      WAITV(0);
      __syncthreads();                       // B2
      if (tid == 0) st_i32(&fS3[p], t + 2);
    }
  }
}

extern "C" void kernel_launch(void* const* d_in, const int* in_sizes, int n_in,
                              void* d_out, int out_size, void* d_ws, size_t ws_size,
                              hipStream_t stream) {
  const float* z    = (const float*)d_in[0];
  // d_in[1] = seq_len (==1024, hard-coded); d_in[2] = W_ih_0 (unused: x0==0)
  const float* Whh0 = (const float*)d_in[3];
  const float* bih0 = (const float*)d_in[4];
  const float* bhh0 = (const float*)d_in[5];
  const float* Wih1 = (const float*)d_in[6];
  const float* Whh1 = (const float*)d_in[7];
  const float* bih1 = (const float*)d_in[8];
  const float* bhh1 = (const float*)d_in[9];
  const float* Wout = (const float*)d_in[10];
  const float* bout = (const float*)d_in[11];
  float* out = (float*)d_out;
  char* ws = (char*)d_ws;

  hipFuncSetAttribute((const void*)gru_pipeline,
                      hipFuncAttributeMaxDynamicSharedMemorySize, SMEM_BYTES);
  hipMemsetAsync(d_ws, 0, 4096, stream);   // flags

  void* args[] = { (void*)&z, (void*)&Whh0, (void*)&bih0, (void*)&bhh0,
                   (void*)&Wih1, (void*)&Whh1, (void*)&bih1, (void*)&bhh1,
                   (void*)&Wout, (void*)&bout, (void*)&out, (void*)&ws };
  hipLaunchCooperativeKernel((void*)gru_pipeline, dim3(NBLK), dim3(512),
                             args, SMEM_BYTES, stream);
}

// Round 8
// 11582.262 us; speedup vs baseline: 1.2718x; 1.0586x over previous
//
#include <hip/hip_runtime.h>

// DecoderGRU: 2-layer GRU (B=64, H=1024, T=1024, OUT=128) + output projection.
// R8 = R7 (self-timed dataflow) + latency-chain trims:
//  - pollers: 2-deep pipelined flag loads (detect lag ~halved), no sleeps
//  - S2's gx staged into LDS by idle waves 4-5 (off the GEMM waves' tail)
//  - elementwise spread over all 512 threads (2 units each)
// Invariants from R1-R7: coherence-point reads cap at ~8.5 B/cyc/CU (hard
// rate cap); critical stages read 128 KB/step -> ~6.3 us floor. This round
// attacks the ~6 us of sync/latency on top of that floor.
//   S0 (blk 0-63):   h0^t = GRU0(h0^{t-1})        [16 units/blk]
//   S1 (blk 64-127): Gx^t = y0^t @ W_ih1^T        [16 units/blk]
//   S2 (blk 128-191): h1^t = GRU1(Gx^t, h1^{t-1}) [16 units/blk]
//   S3 (blk 192-199): out^t = y1^t @ W_out^T + b  [16 cols/blk]

#define NBLK 200
#define SMEM_BYTES 127744
#define H 1024
#define T 1024
#define SLOT(k) (((k) + 3) % 3)

typedef short s16x8 __attribute__((ext_vector_type(8)));
typedef float f32x4 __attribute__((ext_vector_type(4)));

__device__ __forceinline__ unsigned short f2bf(float f) {
  union { float f; unsigned u; } v; v.f = f;
  return (unsigned short)((v.u + 0x7FFFu + ((v.u >> 16) & 1u)) >> 16);
}
__device__ __forceinline__ float sigm(float x) { return 1.f / (1.f + __expf(-x)); }

__device__ __forceinline__ void st_u16(void* p, unsigned short v) {
  __hip_atomic_store((unsigned short*)p, v, __ATOMIC_RELAXED, __HIP_MEMORY_SCOPE_AGENT);
}
__device__ __forceinline__ void st_i32(int* p, int v) {
  __hip_atomic_store(p, v, __ATOMIC_RELAXED, __HIP_MEMORY_SCOPE_AGENT);
}
__device__ __forceinline__ int ld_i32(const int* p) {
  return __hip_atomic_load(p, __ATOMIC_RELAXED, __HIP_MEMORY_SCOPE_AGENT);
}

// ---- coalesced device-coherent loads/stores (bypass L1/L2 -> coherent pt) --
#define GLD(d, p, off) \
  asm volatile("global_load_dwordx4 %0, %1, off offset:" #off " sc0 sc1" \
               : "=v"(d) : "v"(p))
#define GLDG(A, p) GLD(A[0],p,0); GLD(A[1],p,64); GLD(A[2],p,128); GLD(A[3],p,192)
#define WAITV(n) asm volatile("s_waitcnt vmcnt(" #n ")" ::: "memory")
#define TIE4(A) \
  asm volatile("" : "+v"(A[0]),"+v"(A[1]),"+v"(A[2]),"+v"(A[3]))

__device__ __forceinline__ void gst16(s16x8 v, void* p) {
  asm volatile("global_store_dwordx4 %0, %1, off sc0 sc1" :: "v"(p), "v"(v) : "memory");
}
__device__ __forceinline__ void gst16f(f32x4 v, void* p) {
  asm volatile("global_store_dwordx4 %0, %1, off sc0 sc1" :: "v"(p), "v"(v) : "memory");
}
__device__ __forceinline__ void gst4(float v, void* p) {
  asm volatile("global_store_dword %0, %1, off sc0 sc1" :: "v"(p), "v"(v) : "memory");
}
__device__ __forceinline__ void gst4u(unsigned v, void* p) {
  asm volatile("global_store_dword %0, %1, off sc0 sc1" :: "v"(p), "v"(v) : "memory");
}
__device__ __forceinline__ f32x4 gldf(const float* p) {
  f32x4 d;
  asm volatile("global_load_dwordx4 %0, %1, off sc0 sc1" : "=v"(d) : "v"(p));
  return d;
}

// Wave-7 poller, 2-deep pipelined: issue next flag load before consuming the
// current one (compiler tracks __hip_atomic_load -> waits vmcnt(1) only).
// (1) data stage: 64 flags, publish ready[g]=t per 8-flag group;
// (2) optional single gx flag -> ready[8]; (3) optional anti-dep wait.
__device__ __forceinline__ void poller(const int* fd, int dtgt,
                                       const int* fgx, int gtgt,
                                       const int* fa, int na, int atgt,
                                       volatile int* ready, int t, int lane) {
  {
    const int* fp = fd + lane;
    int v = ld_i32(fp);
    for (;;) {
      int vn = ld_i32(fp);
      unsigned long long m = __ballot(v >= dtgt);
      if (lane < 8 && ((m >> (8 * lane)) & 0xFFull) == 0xFFull) ready[lane] = t;
      if (m == ~0ull) break;
      v = vn;
    }
  }
  if (fgx) {
    int v = (lane == 0) ? ld_i32(fgx) : 0x7fffffff;
    for (;;) {
      int vn = (lane == 0) ? ld_i32(fgx) : 0x7fffffff;
      if (__ballot(v < gtgt) == 0ull) break;
      v = vn;
    }
    if (lane == 0) ready[8] = t;
  }
  if (fa) {
    bool act = lane < na;
    const int* fp = fa + (act ? lane : 0);
    int v = act ? ld_i32(fp) : atgt;
    for (;;) {
      int vn = act ? ld_i32(fp) : atgt;
      if (__ballot(v < atgt) == 0ull) break;
      v = vn;
    }
  }
}

#define MF3(Ap, g) { \
  _Pragma("unroll") \
  for (int i = 0; i < 4; ++i) { int kb = (g)*4 + i; \
    s16x8 b0 = *(const s16x8*)(bb + (kb*3+0)*512); \
    s16x8 b1 = *(const s16x8*)(bb + (kb*3+1)*512); \
    s16x8 b2 = *(const s16x8*)(bb + (kb*3+2)*512); \
    a0 = __builtin_amdgcn_mfma_f32_16x16x32_bf16(Ap[i], b0, a0, 0, 0, 0); \
    a1 = __builtin_amdgcn_mfma_f32_16x16x32_bf16(Ap[i], b1, a1, 0, 0, 0); \
    a2 = __builtin_amdgcn_mfma_f32_16x16x32_bf16(Ap[i], b2, a2, 0, 0, 0); } }

#define MF1(Ap, g) { \
  _Pragma("unroll") \
  for (int i = 0; i < 4; ++i) { int kb = (g)*4 + i; \
    s16x8 b0 = *(const s16x8*)(bb + kb*512); \
    a0 = __builtin_amdgcn_mfma_f32_16x16x32_bf16(Ap[i], b0, a0, 0, 0, 0); } }

// N=48 GEMM, group-pipelined: spin ready[g] (LDS), GLDG(4), WAITV(4), MFMA.
__device__ __forceinline__ void gemm48(const unsigned short* arow,
                                       const unsigned short* bb,
                                       volatile int* ready, int t,
                                       float* G, int ldg, int lane, int w) {
  f32x4 a0 = {0,0,0,0}, a1 = {0,0,0,0}, a2 = {0,0,0,0};
  s16x8 A0[4], A1[4];
  while (ready[0] < t) {}
  GLDG(A0, arow);
  while (ready[1] < t) {}
  GLDG(A1, arow + 128);
  #pragma unroll
  for (int g2 = 1; g2 < 4; ++g2) {
    WAITV(4); TIE4(A0); MF3(A0, 2*g2 - 2);
    while (ready[2*g2] < t) {}
    GLDG(A0, arow + g2*256);
    WAITV(4); TIE4(A1); MF3(A1, 2*g2 - 1);
    while (ready[2*g2 + 1] < t) {}
    GLDG(A1, arow + g2*256 + 128);
  }
  WAITV(4); TIE4(A0); MF3(A0, 6);
  WAITV(0); TIE4(A1); MF3(A1, 7);
  int col = lane & 15, r0 = (lane >> 4) * 4;
  #pragma unroll
  for (int r = 0; r < 4; ++r) {
    int brow = w*16 + r0 + r;
    G[brow*ldg +      col] = a0[r];
    G[brow*ldg + 16 + col] = a1[r];
    G[brow*ldg + 32 + col] = a2[r];
  }
}

extern "C" __global__ void __launch_bounds__(512, 1)
gru_pipeline(const float* __restrict__ z,
             const float* __restrict__ Whh0,
             const float* __restrict__ bih0, const float* __restrict__ bhh0,
             const float* __restrict__ Wih1, const float* __restrict__ Whh1,
             const float* __restrict__ bih1, const float* __restrict__ bhh1,
             const float* __restrict__ Wout, const float* __restrict__ bout,
             float* __restrict__ out, char* __restrict__ ws)
{
  extern __shared__ char smem[];
  const int tid  = threadIdx.x;
  const int lane = tid & 63;
  const int w    = tid >> 6;
  const int bid  = blockIdx.x;

  int*            flags = (int*)ws;                     // [4][64] packed
  unsigned short* h0    = (unsigned short*)(ws + 4096); // 3 x 64x1024 bf16
  unsigned short* h1    = (unsigned short*)(ws + 397312);
  float*          gxw   = (float*)(ws + 790528);        // 3 x 64x(64x48) f32

  int role, p;
  if (bid < 64)       { role = 0; p = bid; }
  else if (bid < 128) { role = 1; p = bid - 64; }
  else if (bid < 192) { role = 2; p = bid - 128; }
  else                { role = 3; p = bid - 192; }
  const int base = p * 16;

  unsigned short* frag = (unsigned short*)smem;
  float* G   = (float*)(smem + 98304);    // 64x49
  float* hm  = (float*)(smem + 110848);   // fp32 master state
  float* bi  = (float*)(smem + 114944);
  float* bh  = (float*)(smem + 115136);
  volatile int* ready = (volatile int*)(smem + 115328);  // [9]
  float* gxl = (float*)(smem + 115392);   // S2: staged Gx 64x48
  float* bo  = (float*)(smem + 32768);    // S3 only (past its 32KB frags)

  int* fS0 = flags;       int* fS1 = flags + 64;
  int* fS2 = flags + 128; int* fS3 = flags + 192;

  // ---------------- init: weights -> LDS bf16 B-fragments, prefill ----------
  if (tid < 9) ready[tid] = -1;
  if (role < 3) {
    const float* W = (role == 0) ? Whh0 : (role == 1) ? Wih1 : Whh1;
    for (int q = tid; q < 6144; q += 512) {
      int c = q % 48; int r2 = q / 48; int grp = r2 & 3; int kb = r2 >> 2;
      int g = c >> 4, u = c & 15;
      unsigned short* dst = frag + (kb*3 + g)*512 + (grp*16 + u)*8;
      const float* s = W + (size_t)(g*H + base + u)*H + kb*32 + grp*8;
      #pragma unroll
      for (int j = 0; j < 8; ++j) dst[j] = f2bf(s[j]);
    }
  }
  if (role == 0 || role == 2) {
    const float* bip = (role == 0) ? bih0 : bih1;
    const float* bhp = (role == 0) ? bhh0 : bhh1;
    if (tid < 48) {
      int g = tid >> 4, u = tid & 15;
      bi[tid] = bip[g*H + base + u];
      bh[tid] = bhp[g*H + base + u];
    }
    unsigned short* hb = (role == 0) ? h0 : h1;
    for (int q = tid; q < 1024; q += 512) {
      int b = q >> 4, u = q & 15;
      float v = z[b*H + base + u];
      hm[q] = v;
      st_u16(&hb[2*65536 + b*H + base + u], f2bf(v));   // h^{-1} in slot 2
    }
  } else if (role == 3) {
    for (int q = tid; q < 2048; q += 512) {
      int c = q & 15, grp = (q >> 4) & 3, kb = q >> 6;
      unsigned short* dst = frag + kb*512 + (grp*16 + c)*8;
      const float* s = Wout + (size_t)(base + c)*H + kb*32 + grp*8;
      #pragma unroll
      for (int j = 0; j < 8; ++j) dst[j] = f2bf(s[j]);
    }
    if (tid < 16) bo[tid] = bout[base + tid];
  }
  WAITV(0);
  __syncthreads();
  if (tid == 0) st_i32(&flags[role*64 + p], 1);   // data-step -1 done

  // ---------------- self-timed loops: each role runs t = 0..1023 -----------
  if (role == 0) {
    for (int t = 0; t < 1024; ++t) {
      if (w == 7) {
        poller(fS0, t+1, nullptr, 0, fS1, 64, t-1, ready, t, lane);
      } else if (w < 4) {
        const unsigned short* arow = h0 + SLOT(t-1)*65536
                                     + (w*16 + (lane&15))*H + ((lane>>4)*8);
        gemm48(arow, frag + lane*8, ready, t, G, 49, lane, w);
      }
      __syncthreads();                       // B1: G ready, anti-dep ok
      {                                      // ew: all 512 threads, 2 units
        int b = tid >> 3, u2 = (tid & 7) * 2;
        unsigned short pk[2];
        #pragma unroll
        for (int j = 0; j < 2; ++j) {
          int u = u2 + j;
          float hr = G[b*49 + u]      + bh[u];
          float hz = G[b*49 + 16 + u] + bh[16 + u];
          float hn = G[b*49 + 32 + u] + bh[32 + u];
          float r  = sigm(bi[u] + hr);       // gx = b_ih_0 (x == 0)
          float zg = sigm(bi[16 + u] + hz);
          float n  = tanhf(bi[32 + u] + r * hn);
          int idx = b*16 + u;
          float hp = hm[idx];
          float hv = (1.f - zg) * n + zg * hp;
          hm[idx] = hv;
          pk[j] = f2bf(hv);
        }
        gst4u((unsigned)pk[0] | ((unsigned)pk[1] << 16),
              &h0[SLOT(t)*65536 + b*H + base + u2]);
      }
      WAITV(0);
      __syncthreads();                       // B2: stores drained block-wide
      if (tid == 0) st_i32(&fS0[p], t + 2);
    }
  } else if (role == 1) {
    for (int t = 0; t < 1024; ++t) {
      if (w == 7) {
        poller(fS0, t+2, nullptr, 0, fS2, 64, t-1, ready, t, lane);
      } else if (w < 4) {
        const unsigned short* arow = h0 + SLOT(t)*65536
                                     + (w*16 + (lane&15))*H + ((lane>>4)*8);
        gemm48(arow, frag + lane*8, ready, t, G, 48, lane, w);
      }
      __syncthreads();                       // B1
      {
        float* dst = gxw + (size_t)(t % 3)*196608 + p*3072;
        for (int c2 = tid; c2 < 768; c2 += 512) {
          int b = c2 / 12, k = c2 % 12;
          gst16f(*(f32x4*)(G + b*48 + k*4), dst + b*48 + k*4);
        }
      }
      WAITV(0);
      __syncthreads();                       // B2
      if (tid == 0) st_i32(&fS1[p], t + 2);
    }
  } else if (role == 2) {
    for (int t = 0; t < 1024; ++t) {
      if (w == 7) {
        poller(fS2, t+1, &fS1[p], t+2, fS3, 8, t-1, ready, t, lane);
      } else if (w < 4) {
        const unsigned short* arow = h1 + SLOT(t-1)*65536
                                     + (w*16 + (lane&15))*H + ((lane>>4)*8);
        gemm48(arow, frag + lane*8, ready, t, G, 49, lane, w);
      } else if (w < 6) {
        // waves 4-5: stage Gx^t -> LDS, parallel with the h1 GEMM
        int idx = tid - 256;                 // 0..127
        int b = idx >> 1, u0 = (idx & 1) * 8;
        while (ready[8] < t) {}
        const float* gxp = gxw + (size_t)(t % 3)*196608 + p*3072 + b*48 + u0;
        f32x4 g0 = gldf(gxp);      f32x4 g1 = gldf(gxp + 4);
        f32x4 g2 = gldf(gxp + 16); f32x4 g3 = gldf(gxp + 20);
        f32x4 g4 = gldf(gxp + 32); f32x4 g5 = gldf(gxp + 36);
        WAITV(0);
        asm volatile("" : "+v"(g0), "+v"(g1), "+v"(g2),
                          "+v"(g3), "+v"(g4), "+v"(g5));
        *(f32x4*)(gxl + b*48 + u0)      = g0; *(f32x4*)(gxl + b*48 + u0 + 4)      = g1;
        *(f32x4*)(gxl + b*48 + 16 + u0) = g2; *(f32x4*)(gxl + b*48 + 16 + u0 + 4) = g3;
        *(f32x4*)(gxl + b*48 + 32 + u0) = g4; *(f32x4*)(gxl + b*48 + 32 + u0 + 4) = g5;
      }
      __syncthreads();                       // B1: G + gxl + anti-dep ok
      {                                      // ew: all 512 threads, 2 units
        int b = tid >> 3, u2 = (tid & 7) * 2;
        unsigned short pk[2];
        #pragma unroll
        for (int j = 0; j < 2; ++j) {
          int u = u2 + j;
          float xr = gxl[b*48 + u]      + bi[u];
          float xz = gxl[b*48 + 16 + u] + bi[16 + u];
          float xn = gxl[b*48 + 32 + u] + bi[32 + u];
          float hr = G[b*49 + u]      + bh[u];
          float hz = G[b*49 + 16 + u] + bh[16 + u];
          float hn = G[b*49 + 32 + u] + bh[32 + u];
          float r  = sigm(xr + hr);
          float zg = sigm(xz + hz);
          float n  = tanhf(xn + r * hn);
          int idx = b*16 + u;
          float hp = hm[idx];
          float hv = (1.f - zg) * n + zg * hp;
          hm[idx] = hv;
          pk[j] = f2bf(hv);
        }
        gst4u((unsigned)pk[0] | ((unsigned)pk[1] << 16),
              &h1[(t % 3)*65536 + b*H + base + u2]);
      }
      WAITV(0);
      __syncthreads();                       // B2
      if (tid == 0) st_i32(&fS2[p], t + 2);
    }
  } else {
    for (int t = 0; t < 1024; ++t) {
      if (w == 7) {
        poller(fS2, t+2, nullptr, 0, nullptr, 0, 0, ready, t, lane);
      } else if (w < 4) {
        const unsigned short* arow = h1 + (t % 3)*65536
                                     + (w*16 + (lane&15))*H + ((lane>>4)*8);
        const unsigned short* bb = frag + lane*8;
        f32x4 a0 = {0,0,0,0};
        s16x8 A0[4], A1[4];
        while (ready[0] < t) {}
        GLDG(A0, arow);
        while (ready[1] < t) {}
        GLDG(A1, arow + 128);
        #pragma unroll
        for (int g2i = 1; g2i < 4; ++g2i) {
          WAITV(4); TIE4(A0); MF1(A0, 2*g2i - 2);
          while (ready[2*g2i] < t) {}
          GLDG(A0, arow + g2i*256);
          WAITV(4); TIE4(A1); MF1(A1, 2*g2i - 1);
          while (ready[2*g2i + 1] < t) {}
          GLDG(A1, arow + g2i*256 + 128);
        }
        WAITV(4); TIE4(A0); MF1(A0, 6);
        WAITV(0); TIE4(A1); MF1(A1, 7);
        int col = lane & 15, r0 = (lane >> 4) * 4;
        #pragma unroll
        for (int r = 0; r < 4; ++r) {
          int brow = w*16 + r0 + r;
          gst4(a0[r] + bo[col], out + (size_t)(brow*T + t)*128 + base + col);
        }
      }
      WAITV(0);
      __syncthreads();                       // B2
      if (tid == 0) st_i32(&fS3[p], t + 2);
    }
  }
}

extern "C" void kernel_launch(void* const* d_in, const int* in_sizes, int n_in,
                              void* d_out, int out_size, void* d_ws, size_t ws_size,
                              hipStream_t stream) {
  const float* z    = (const float*)d_in[0];
  // d_in[1] = seq_len (==1024, hard-coded); d_in[2] = W_ih_0 (unused: x0==0)
  const float* Whh0 = (const float*)d_in[3];
  const float* bih0 = (const float*)d_in[4];
  const float* bhh0 = (const float*)d_in[5];
  const float* Wih1 = (const float*)d_in[6];
  const float* Whh1 = (const float*)d_in[7];
  const float* bih1 = (const float*)d_in[8];
  const float* bhh1 = (const float*)d_in[9];
  const float* Wout = (const float*)d_in[10];
  const float* bout = (const float*)d_in[11];
  float* out = (float*)d_out;
  char* ws = (char*)d_ws;

  hipFuncSetAttribute((const void*)gru_pipeline,
                      hipFuncAttributeMaxDynamicSharedMemorySize, SMEM_BYTES);
  hipMemsetAsync(d_ws, 0, 4096, stream);   // flags

  void* args[] = { (void*)&z, (void*)&Whh0, (void*)&bih0, (void*)&bhh0,
                   (void*)&Wih1, (void*)&Whh1, (void*)&bih1, (void*)&bhh1,
                   (void*)&Wout, (void*)&bout, (void*)&out, (void*)&ws };
  hipLaunchCooperativeKernel((void*)gru_pipeline, dim3(NBLK), dim3(512),
                             args, SMEM_BYTES, stream);
}

// Round 9
// 11516.904 us; speedup vs baseline: 1.2790x; 1.0057x over previous
//
#include <hip/hip_runtime.h>

// DecoderGRU: 2-layer GRU (B=64, H=1024, T=1024, OUT=128) + output projection.
// R9 = R8's self-timed pipeline with NO intra-loop barriers (roles 0-2).
// Waves specialize: 0-3 GEMM (free-running, double-buffered G), 4-6 ew
// (+gx staging for S2, double-buffered gxl), 7 poller. Monotone LDS flags
// (gdone/ewflag/gxst/ewdone) replace __syncthreads; ew/drain/flag of step t
// overlaps GEMM of t+1. Cross-block flag protocol identical to R8.
// Model: per-CU sc1 reads are MSHR x latency bound (~8.5 B/cyc); 128 KB/step
// GEMM read = 6.4 us floor; R9 removes the ~3-4 us of in-block serialization.
//   S0 (blk 0-63):   h0^t = GRU0(h0^{t-1})        [16 units/blk]
//   S1 (blk 64-127): Gx^t = y0^t @ W_ih1^T        [16 units/blk]
//   S2 (blk 128-191): h1^t = GRU1(Gx^t, h1^{t-1}) [16 units/blk]
//   S3 (blk 192-199): out^t = y1^t @ W_out^T + b  [16 cols/blk]

#define NBLK 200
#define SMEM_BYTES 152576
#define H 1024
#define T 1024
#define SLOT(k) (((k) + 3) % 3)
#define MEMBAR asm volatile("" ::: "memory")

typedef short s16x8 __attribute__((ext_vector_type(8)));
typedef float f32x4 __attribute__((ext_vector_type(4)));

__device__ __forceinline__ unsigned short f2bf(float f) {
  union { float f; unsigned u; } v; v.f = f;
  return (unsigned short)((v.u + 0x7FFFu + ((v.u >> 16) & 1u)) >> 16);
}
__device__ __forceinline__ float sigm(float x) { return 1.f / (1.f + __expf(-x)); }

__device__ __forceinline__ void st_u16(void* p, unsigned short v) {
  __hip_atomic_store((unsigned short*)p, v, __ATOMIC_RELAXED, __HIP_MEMORY_SCOPE_AGENT);
}
__device__ __forceinline__ void st_i32(int* p, int v) {
  __hip_atomic_store(p, v, __ATOMIC_RELAXED, __HIP_MEMORY_SCOPE_AGENT);
}
__device__ __forceinline__ int ld_i32(const int* p) {
  return __hip_atomic_load(p, __ATOMIC_RELAXED, __HIP_MEMORY_SCOPE_AGENT);
}

// ---- coalesced device-coherent loads/stores (bypass L1/L2 -> coherent pt) --
#define GLD(d, p, off) \
  asm volatile("global_load_dwordx4 %0, %1, off offset:" #off " sc0 sc1" \
               : "=v"(d) : "v"(p))
#define GLDG(A, p) GLD(A[0],p,0); GLD(A[1],p,64); GLD(A[2],p,128); GLD(A[3],p,192)
#define WAITV(n) asm volatile("s_waitcnt vmcnt(" #n ")" ::: "memory")
#define TIE4(A) \
  asm volatile("" : "+v"(A[0]),"+v"(A[1]),"+v"(A[2]),"+v"(A[3]))

__device__ __forceinline__ void gst16f(f32x4 v, void* p) {
  asm volatile("global_store_dwordx4 %0, %1, off sc0 sc1" :: "v"(p), "v"(v) : "memory");
}
__device__ __forceinline__ void gst4(float v, void* p) {
  asm volatile("global_store_dword %0, %1, off sc0 sc1" :: "v"(p), "v"(v) : "memory");
}
__device__ __forceinline__ void gst4u(unsigned v, void* p) {
  asm volatile("global_store_dword %0, %1, off sc0 sc1" :: "v"(p), "v"(v) : "memory");
}
__device__ __forceinline__ f32x4 gldf(const float* p) {
  f32x4 d;
  asm volatile("global_load_dwordx4 %0, %1, off sc0 sc1" : "=v"(d) : "v"(p));
  return d;
}

// Wave-7 poller, 2-deep pipelined (identical to R8).
__device__ __forceinline__ void poller(const int* fd, int dtgt,
                                       const int* fgx, int gtgt,
                                       const int* fa, int na, int atgt,
                                       volatile int* ready, int t, int lane) {
  {
    const int* fp = fd + lane;
    int v = ld_i32(fp);
    for (;;) {
      int vn = ld_i32(fp);
      unsigned long long m = __ballot(v >= dtgt);
      if (lane < 8 && ((m >> (8 * lane)) & 0xFFull) == 0xFFull) ready[lane] = t;
      if (m == ~0ull) break;
      v = vn;
    }
  }
  if (fgx) {
    int v = (lane == 0) ? ld_i32(fgx) : 0x7fffffff;
    for (;;) {
      int vn = (lane == 0) ? ld_i32(fgx) : 0x7fffffff;
      if (__ballot(v < gtgt) == 0ull) break;
      v = vn;
    }
    if (lane == 0) ready[8] = t;
  }
  if (fa) {
    bool act = lane < na;
    const int* fp = fa + (act ? lane : 0);
    int v = act ? ld_i32(fp) : atgt;
    for (;;) {
      int vn = act ? ld_i32(fp) : atgt;
      if (__ballot(v < atgt) == 0ull) break;
      v = vn;
    }
  }
}

#define MF3(Ap, g) { \
  _Pragma("unroll") \
  for (int i = 0; i < 4; ++i) { int kb = (g)*4 + i; \
    s16x8 b0 = *(const s16x8*)(bb + (kb*3+0)*512); \
    s16x8 b1 = *(const s16x8*)(bb + (kb*3+1)*512); \
    s16x8 b2 = *(const s16x8*)(bb + (kb*3+2)*512); \
    a0 = __builtin_amdgcn_mfma_f32_16x16x32_bf16(Ap[i], b0, a0, 0, 0, 0); \
    a1 = __builtin_amdgcn_mfma_f32_16x16x32_bf16(Ap[i], b1, a1, 0, 0, 0); \
    a2 = __builtin_amdgcn_mfma_f32_16x16x32_bf16(Ap[i], b2, a2, 0, 0, 0); } }

#define MF1(Ap, g) { \
  _Pragma("unroll") \
  for (int i = 0; i < 4; ++i) { int kb = (g)*4 + i; \
    s16x8 b0 = *(const s16x8*)(bb + kb*512); \
    a0 = __builtin_amdgcn_mfma_f32_16x16x32_bf16(Ap[i], b0, a0, 0, 0, 0); } }

// N=48 GEMM, group-pipelined (identical compute to R8).
__device__ __forceinline__ void gemm48(const unsigned short* arow,
                                       const unsigned short* bb,
                                       volatile int* ready, int t,
                                       float* G, int ldg, int lane, int w) {
  f32x4 a0 = {0,0,0,0}, a1 = {0,0,0,0}, a2 = {0,0,0,0};
  s16x8 A0[4], A1[4];
  while (ready[0] < t) {}
  MEMBAR;
  GLDG(A0, arow);
  while (ready[1] < t) {}
  MEMBAR;
  GLDG(A1, arow + 128);
  #pragma unroll
  for (int g2 = 1; g2 < 4; ++g2) {
    WAITV(4); TIE4(A0); MF3(A0, 2*g2 - 2);
    while (ready[2*g2] < t) {}
    MEMBAR;
    GLDG(A0, arow + g2*256);
    WAITV(4); TIE4(A1); MF3(A1, 2*g2 - 1);
    while (ready[2*g2 + 1] < t) {}
    MEMBAR;
    GLDG(A1, arow + g2*256 + 128);
  }
  WAITV(4); TIE4(A0); MF3(A0, 6);
  WAITV(0); TIE4(A1); MF3(A1, 7);
  int col = lane & 15, r0 = (lane >> 4) * 4;
  #pragma unroll
  for (int r = 0; r < 4; ++r) {
    int brow = w*16 + r0 + r;
    G[brow*ldg +      col] = a0[r];
    G[brow*ldg + 16 + col] = a1[r];
    G[brow*ldg + 32 + col] = a2[r];
  }
}

extern "C" __global__ void __launch_bounds__(512, 1)
gru_pipeline(const float* __restrict__ z,
             const float* __restrict__ Whh0,
             const float* __restrict__ bih0, const float* __restrict__ bhh0,
             const float* __restrict__ Wih1, const float* __restrict__ Whh1,
             const float* __restrict__ bih1, const float* __restrict__ bhh1,
             const float* __restrict__ Wout, const float* __restrict__ bout,
             float* __restrict__ out, char* __restrict__ ws)
{
  extern __shared__ char smem[];
  const int tid  = threadIdx.x;
  const int lane = tid & 63;
  const int w    = tid >> 6;
  const int bid  = blockIdx.x;

  int*            flags = (int*)ws;                     // [4][64] packed
  unsigned short* h0    = (unsigned short*)(ws + 4096); // 3 x 64x1024 bf16
  unsigned short* h1    = (unsigned short*)(ws + 397312);
  float*          gxw   = (float*)(ws + 790528);        // 3 x 64x(64x48) f32

  int role, p;
  if (bid < 64)       { role = 0; p = bid; }
  else if (bid < 128) { role = 1; p = bid - 64; }
  else if (bid < 192) { role = 2; p = bid - 128; }
  else                { role = 3; p = bid - 192; }
  const int base = p * 16;

  unsigned short* frag = (unsigned short*)smem;
  float* G   = (float*)(smem + 98304);    // 2 x 64x49 f32 (double buffer)
  float* hm  = (float*)(smem + 123392);   // fp32 master state
  float* bi  = (float*)(smem + 127488);
  float* bh  = (float*)(smem + 127680);
  volatile int* ready  = (volatile int*)(smem + 127872);  // [9]
  volatile int* gdone  = (volatile int*)(smem + 127936);  // [4]
  volatile int* ewflag = (volatile int*)(smem + 127952);  // [3]
  volatile int* gxst   = (volatile int*)(smem + 127968);  // [3]
  volatile int* ewdone = (volatile int*)(smem + 127984);  // [1]
  float* gxl = (float*)(smem + 128000);   // S2: 2 x 64x48 f32 (double buffer)
  float* bo  = (float*)(smem + 32768);    // S3 only (past its 32KB frags)

  int* fS0 = flags;       int* fS1 = flags + 64;
  int* fS2 = flags + 128; int* fS3 = flags + 192;

  // ---------------- init: weights -> LDS bf16 B-fragments, prefill ----------
  if (tid < 9) ready[tid] = -1;
  if (tid == 0) {
    gdone[0] = gdone[1] = gdone[2] = gdone[3] = -1;
    ewflag[0] = ewflag[1] = ewflag[2] = -1;
    gxst[0] = gxst[1] = gxst[2] = -1;
    *ewdone = -1;
  }
  if (role < 3) {
    const float* W = (role == 0) ? Whh0 : (role == 1) ? Wih1 : Whh1;
    for (int q = tid; q < 6144; q += 512) {
      int c = q % 48; int r2 = q / 48; int grp = r2 & 3; int kb = r2 >> 2;
      int g = c >> 4, u = c & 15;
      unsigned short* dst = frag + (kb*3 + g)*512 + (grp*16 + u)*8;
      const float* s = W + (size_t)(g*H + base + u)*H + kb*32 + grp*8;
      #pragma unroll
      for (int j = 0; j < 8; ++j) dst[j] = f2bf(s[j]);
    }
  }
  if (role == 0 || role == 2) {
    const float* bip = (role == 0) ? bih0 : bih1;
    const float* bhp = (role == 0) ? bhh0 : bhh1;
    if (tid < 48) {
      int g = tid >> 4, u = tid & 15;
      bi[tid] = bip[g*H + base + u];
      bh[tid] = bhp[g*H + base + u];
    }
    unsigned short* hb = (role == 0) ? h0 : h1;
    for (int q = tid; q < 1024; q += 512) {
      int b = q >> 4, u = q & 15;
      float v = z[b*H + base + u];
      hm[q] = v;
      st_u16(&hb[2*65536 + b*H + base + u], f2bf(v));   // h^{-1} in slot 2
    }
  } else if (role == 3) {
    for (int q = tid; q < 2048; q += 512) {
      int c = q & 15, grp = (q >> 4) & 3, kb = q >> 6;
      unsigned short* dst = frag + kb*512 + (grp*16 + c)*8;
      const float* s = Wout + (size_t)(base + c)*H + kb*32 + grp*8;
      #pragma unroll
      for (int j = 0; j < 8; ++j) dst[j] = f2bf(s[j]);
    }
    if (tid < 16) bo[tid] = bout[base + tid];
  }
  WAITV(0);
  __syncthreads();
  if (tid == 0) st_i32(&flags[role*64 + p], 1);   // data-step -1 done

  // ---------------- barrier-free steady state (roles 0-2) ------------------
  if (role < 3) {
    unsigned short* hsrc = (role == 2) ? h1 : h0;   // GEMM A source
    if (w < 4) {
      // ---- GEMM waves: free-running, double-buffered G ----
      const int ldg = (role == 1) ? 48 : 49;
      const int dt  = (role == 1) ? 0 : 1;          // A slot: t-dt
      for (int t = 0; t < 1024; ++t) {
        while (*ewdone < t - 2) {}
        MEMBAR;
        const unsigned short* arow = hsrc + SLOT(t - dt)*65536
                                     + (w*16 + (lane&15))*H + ((lane>>4)*8);
        gemm48(arow, frag + lane*8, ready, t, G + (t&1)*3136, ldg, lane, w);
        MEMBAR;
        gdone[w] = t;
      }
    } else if (w == 7) {
      // ---- poller wave (identical targets to R8) ----
      for (int t = 0; t < 1024; ++t) {
        if (role == 0)      poller(fS0, t+1, nullptr, 0, fS1, 64, t-1, ready, t, lane);
        else if (role == 1) poller(fS0, t+2, nullptr, 0, fS2, 64, t-1, ready, t, lane);
        else                poller(fS2, t+1, &fS1[p], t+2, fS3, 8, t-1, ready, t, lane);
      }
    } else {
      // ---- ew waves 4-6 ----
      const int wv = w - 4;
      const int ewt = wv*64 + lane;                 // 0..191
      int* fme = flags + role*64 + p;
      for (int t = 0; t < 1024; ++t) {
        if (role == 2) {
          // stage gx^t -> gxl[t&1] (coalesced, off the GEMM waves)
          while (ready[8] < t) {}
          MEMBAR;
          const float* gxp = gxw + (size_t)(t % 3)*196608 + p*3072
                             + wv*1024 + lane*16;
          f32x4 ga = gldf(gxp), gb = gldf(gxp + 4),
                gc = gldf(gxp + 8), gd = gldf(gxp + 12);
          WAITV(0);
          asm volatile("" : "+v"(ga), "+v"(gb), "+v"(gc), "+v"(gd));
          float* dstl = gxl + (t&1)*3072 + wv*1024 + lane*16;
          *(f32x4*)(dstl)      = ga; *(f32x4*)(dstl + 4)  = gb;
          *(f32x4*)(dstl + 8)  = gc; *(f32x4*)(dstl + 12) = gd;
          MEMBAR;
          gxst[wv] = t;
          while (gxst[0] < t || gxst[1] < t || gxst[2] < t) {}
          MEMBAR;
        }
        while (gdone[0] < t || gdone[1] < t || gdone[2] < t || gdone[3] < t) {}
        MEMBAR;
        float* Gt = G + (t&1)*3136;
        if (role == 1) {
          // dump Gx to global
          float* dst = gxw + (size_t)(t % 3)*196608 + p*3072;
          for (int c2 = ewt; c2 < 768; c2 += 192)
            gst16f(*(f32x4*)(Gt + c2*4), dst + c2*4);
        } else {
          float* gx2 = gxl + (t&1)*3072;
          unsigned short* hdst = hsrc + SLOT(t)*65536;
          for (int q = ewt; q < 512; q += 192) {
            int b = q >> 3, u2 = (q & 7) * 2;
            unsigned short pk[2];
            #pragma unroll
            for (int j = 0; j < 2; ++j) {
              int u = u2 + j;
              float xr, xz, xn;
              if (role == 0) {                 // gx = b_ih_0 (x == 0)
                xr = bi[u]; xz = bi[16 + u]; xn = bi[32 + u];
              } else {
                xr = gx2[b*48 + u]      + bi[u];
                xz = gx2[b*48 + 16 + u] + bi[16 + u];
                xn = gx2[b*48 + 32 + u] + bi[32 + u];
              }
              float hr = Gt[b*49 + u]      + bh[u];
              float hz = Gt[b*49 + 16 + u] + bh[16 + u];
              float hn = Gt[b*49 + 32 + u] + bh[32 + u];
              float r  = sigm(xr + hr);
              float zg = sigm(xz + hz);
              float n  = tanhf(xn + r * hn);
              int idx = b*16 + u;
              float hp = hm[idx];
              float hv = (1.f - zg) * n + zg * hp;
              hm[idx] = hv;
              pk[j] = f2bf(hv);
            }
            gst4u((unsigned)pk[0] | ((unsigned)pk[1] << 16),
                  &hdst[b*H + base + u2]);
          }
        }
        WAITV(0);
        MEMBAR;
        ewflag[wv] = t;
        if (wv == 0) {
          while (ewflag[1] < t || ewflag[2] < t) {}
          MEMBAR;
          if (lane == 0) st_i32(fme, t + 2);
          MEMBAR;
          *ewdone = t;
        }
      }
    }
  } else {
    // ---- S3: as R8 (not critical; keeps its per-step block barrier) ----
    for (int t = 0; t < 1024; ++t) {
      if (w == 7) {
        poller(fS2, t+2, nullptr, 0, nullptr, 0, 0, ready, t, lane);
      } else if (w < 4) {
        const unsigned short* arow = h1 + (t % 3)*65536
                                     + (w*16 + (lane&15))*H + ((lane>>4)*8);
        const unsigned short* bb = frag + lane*8;
        f32x4 a0 = {0,0,0,0};
        s16x8 A0[4], A1[4];
        while (ready[0] < t) {}
        MEMBAR;
        GLDG(A0, arow);
        while (ready[1] < t) {}
        MEMBAR;
        GLDG(A1, arow + 128);
        #pragma unroll
        for (int g2i = 1; g2i < 4; ++g2i) {
          WAITV(4); TIE4(A0); MF1(A0, 2*g2i - 2);
          while (ready[2*g2i] < t) {}
          MEMBAR;
          GLDG(A0, arow + g2i*256);
          WAITV(4); TIE4(A1); MF1(A1, 2*g2i - 1);
          while (ready[2*g2i + 1] < t) {}
          MEMBAR;
          GLDG(A1, arow + g2i*256 + 128);
        }
        WAITV(4); TIE4(A0); MF1(A0, 6);
        WAITV(0); TIE4(A1); MF1(A1, 7);
        int col = lane & 15, r0 = (lane >> 4) * 4;
        #pragma unroll
        for (int r = 0; r < 4; ++r) {
          int brow = w*16 + r0 + r;
          gst4(a0[r] + bo[col], out + (size_t)(brow*T + t)*128 + base + col);
        }
      }
      WAITV(0);
      __syncthreads();
      if (tid == 0) st_i32(&fS3[p], t + 2);
    }
  }
}

extern "C" void kernel_launch(void* const* d_in, const int* in_sizes, int n_in,
                              void* d_out, int out_size, void* d_ws, size_t ws_size,
                              hipStream_t stream) {
  const float* z    = (const float*)d_in[0];
  // d_in[1] = seq_len (==1024, hard-coded); d_in[2] = W_ih_0 (unused: x0==0)
  const float* Whh0 = (const float*)d_in[3];
  const float* bih0 = (const float*)d_in[4];
  const float* bhh0 = (const float*)d_in[5];
  const float* Wih1 = (const float*)d_in[6];
  const float* Whh1 = (const float*)d_in[7];
  const float* bih1 = (const float*)d_in[8];
  const float* bhh1 = (const float*)d_in[9];
  const float* Wout = (const float*)d_in[10];
  const float* bout = (const float*)d_in[11];
  float* out = (float*)d_out;
  char* ws = (char*)d_ws;

  hipFuncSetAttribute((const void*)gru_pipeline,
                      hipFuncAttributeMaxDynamicSharedMemorySize, SMEM_BYTES);
  hipMemsetAsync(d_ws, 0, 4096, stream);   // flags

  void* args[] = { (void*)&z, (void*)&Whh0, (void*)&bih0, (void*)&bhh0,
                   (void*)&Wih1, (void*)&Whh1, (void*)&bih1, (void*)&bhh1,
                   (void*)&Wout, (void*)&bout, (void*)&out, (void*)&ws };
  hipLaunchCooperativeKernel((void*)gru_pipeline, dim3(NBLK), dim3(512),
                             args, SMEM_BYTES, stream);
}